// Round 11
// baseline (494.790 us; speedup 1.0000x reference)
//
#include <hip/hip_runtime.h>
#include <math.h>

#define NN 4096
#define NE 65536
#define DIN 128
#define DM 256
#define NH 4
#define NL 3
#define NCH 4
#define TPC (NN / 64 / NCH)  // 16 KV tiles per chunk
#define NBKT 16384           // bias buckets: (r>>4) * 64 + (c>>6)
#define LOG2E 1.44269504f

typedef __attribute__((ext_vector_type(8))) short bf16x8;
typedef __attribute__((ext_vector_type(4))) float f32x4;

__device__ inline ushort f2b(float f) {
    union { float f; uint u; } v; v.f = f;
    uint r = v.u + 0x7fffu + ((v.u >> 16) & 1u);
    return (ushort)(r >> 16);
}

__device__ inline uint cvt_pk_bf16(float lo, float hi) {
    uint r;
    asm("v_cvt_pk_bf16_f32 %0, %1, %2" : "=v"(r) : "v"(lo), "v"(hi));
    return r;
}

__device__ inline void gl_lds16(const ushort* g, ushort* l) {
    __builtin_amdgcn_global_load_lds(
        (const __attribute__((address_space(1))) void*)g,
        (__attribute__((address_space(3))) void*)l, 16, 0, 0);
}

// ---------------- preprocessing ----------------

__global__ void k_edge1(const int* __restrict__ row, const int* __restrict__ col,
                        uint* __restrict__ bitmap, int* __restrict__ cnt_c,
                        int* __restrict__ bcnt, unsigned char* __restrict__ flag) {
    int e = blockIdx.x * 256 + threadIdx.x;
    if (e >= NE) return;
    int r = row[e], c = col[e];
    atomicAdd(&cnt_c[c], 1);
    uint idx = (uint)r * 4096u + (uint)c;
    uint m = 1u << (idx & 31);
    uint old = atomicOr(&bitmap[idx >> 5], m);
    int isnew = (old & m) ? 0 : 1;
    flag[e] = (unsigned char)isnew;
    if (isnew) atomicAdd(&bcnt[(r >> 4) * 64 + (c >> 6)], 1);
}

// fills CSC and per-(wave,tile) bias entries; sigmoids premultiplied by log2e (exp2 domain)
__global__ void k_edge2(const int* __restrict__ row, const int* __restrict__ col,
                        const unsigned char* __restrict__ flag,
                        const int* __restrict__ sc, int* __restrict__ fc, int* __restrict__ csc_row,
                        const int* __restrict__ bstart, int* __restrict__ bfill,
                        uint* __restrict__ entcomb,
                        const float* __restrict__ ew, const float* __restrict__ eb) {
    int e = blockIdx.x * 256 + threadIdx.x;
    if (e >= NE) return;
    int r = row[e], c = col[e];
    csc_row[sc[c] + atomicAdd(&fc[c], 1)] = r;
    if (flag[e]) {
        int key = (r >> 4) * 64 + (c >> 6);
        int pos = bstart[key] + atomicAdd(&bfill[key], 1);
        uint idx = (uint)(((r & 15) << 6) | (c & 63));
        float fr = (float)r, fc2 = (float)c;
#pragma unroll
        for (int h = 0; h < NH; ++h) {
            float arg = ew[h * 3 + 0] * fr + ew[h * 3 + 1] * fc2 + ew[h * 3 + 2] + eb[h];
            float sig = LOG2E / (1.f + __expf(-arg));
            entcomb[(long)h * NE + pos] = idx | ((uint)f2b(sig) << 16);
        }
    }
}

// exclusive scan of N ints -> start[0..N]
template <int N>
__global__ void k_scan(const int* __restrict__ cnt, int* __restrict__ start) {
    __shared__ int part[256];
    const int C = N / 256;
    int t = threadIdx.x;
    int s = 0;
    for (int i = 0; i < C; ++i) s += cnt[t * C + i];
    part[t] = s;
    __syncthreads();
    if (t == 0) {
        int acc = 0;
        for (int i = 0; i < 256; ++i) { int v = part[i]; part[i] = acc; acc += v; }
        start[N] = acc;
    }
    __syncthreads();
    int acc = part[t];
    for (int i = 0; i < C; ++i) { start[t * C + i] = acc; acc += cnt[t * C + i]; }
}

__global__ void k_dinv(const int* __restrict__ cnt_c, float* __restrict__ dinv) {
    int i = blockIdx.x * 256 + threadIdx.x;
    if (i < NN) dinv[i] = 1.0f / sqrtf((float)(cnt_c[i] + 1));
}

// ---------------- f32 -> bf16 batch convert (y==1: Q rows scaled by 0.125*log2e) ----------------
struct CvtP { const float* s[8]; ushort* d[8]; int n[8]; };
__global__ void k_cvt(CvtP p) {
    int y = blockIdx.y;
    int base = (blockIdx.x * 256 + threadIdx.x) * 4;
    if (base >= p.n[y]) return;
    float4 v = *(const float4*)(p.s[y] + base);
    float sc = 1.f;
    if (y == 1 && ((base >> 8) % 768) < 256) sc = 0.125f * LOG2E;  // softmax scale + exp2 domain
    ushort4 o;
    o.x = f2b(v.x * sc); o.y = f2b(v.y * sc); o.z = f2b(v.z * sc); o.w = f2b(v.w * sc);
    *(ushort4*)(p.d[y] + base) = o;
}

__global__ void k_scaleb(const float* __restrict__ b, float* __restrict__ o) {
    int i = blockIdx.x * 256 + threadIdx.x;
    if (i < NL * 768) o[i] = b[i] * (((i % 768) < 256) ? 0.125f * LOG2E : 1.f);
}

// ---------------- bf16 MFMA GEMM: C = act(A @ B^T + bias) ----------------
// FLAGS: 1 = f32 Cf, 2 = bf16 Cb, 4 = relu, 8 = bf16 TRANSPOSED (Cb[c*ldc+r]),
// 16 = qkv-split: col<512 -> Cb[r*512+c], col>=512 -> Cb2[(c-512)*NN + r] transposed
template <int FLAGS>
__global__ __launch_bounds__(256) void k_gemm_b(
    const ushort* __restrict__ A, int lda,
    const ushort* __restrict__ B, int ldb,
    float* __restrict__ Cf, ushort* __restrict__ Cb, ushort* __restrict__ Cb2, int ldc,
    int K, const float* __restrict__ bias) {
    __shared__ ushort As[128 * 64];
    __shared__ ushort Bs[128 * 64];
    const int tid = threadIdx.x;
    const int w = tid >> 6, l = tid & 63;
    const int l15 = l & 15, l4 = l >> 4;
    const int row0 = blockIdx.y * 128, col0 = blockIdx.x * 128;
    const int wm = (w >> 1) * 64, wn = (w & 1) * 64;
    f32x4 acc[4][4];
#pragma unroll
    for (int i = 0; i < 4; ++i)
#pragma unroll
        for (int j = 0; j < 4; ++j) acc[i][j] = (f32x4){0.f, 0.f, 0.f, 0.f};
    for (int k0 = 0; k0 < K; k0 += 64) {
#pragma unroll
        for (int i = 0; i < 4; ++i) {
            int ci = tid + 256 * i;
            int r = ci >> 3, s = ci & 7;
            bf16x8 va = *(const bf16x8*)(A + (long)(row0 + r) * lda + k0 + s * 8);
            *(bf16x8*)&As[r * 64 + ((s ^ (r & 7)) * 8)] = va;
            bf16x8 vb = *(const bf16x8*)(B + (long)(col0 + r) * ldb + k0 + s * 8);
            *(bf16x8*)&Bs[r * 64 + ((s ^ (r & 7)) * 8)] = vb;
        }
        __syncthreads();
#pragma unroll
        for (int kk = 0; kk < 2; ++kk) {
            bf16x8 af[4], bfr[4];
#pragma unroll
            for (int i = 0; i < 4; ++i) {
                int ar = wm + i * 16 + l15;
                af[i] = *(const bf16x8*)&As[ar * 64 + (((kk * 4 + l4) ^ (ar & 7)) * 8)];
                int br = wn + i * 16 + l15;
                bfr[i] = *(const bf16x8*)&Bs[br * 64 + (((kk * 4 + l4) ^ (br & 7)) * 8)];
            }
#pragma unroll
            for (int i = 0; i < 4; ++i)
#pragma unroll
                for (int j = 0; j < 4; ++j)
                    acc[i][j] = __builtin_amdgcn_mfma_f32_16x16x32_bf16(af[i], bfr[j], acc[i][j], 0, 0, 0);
        }
        __syncthreads();
    }
#pragma unroll
    for (int i = 0; i < 4; ++i)
#pragma unroll
        for (int j = 0; j < 4; ++j) {
            int rb = row0 + wm + i * 16;
            int cb = col0 + wn + j * 16 + l15;
            float bv = bias ? bias[cb] : 0.f;
            if (FLAGS & 16) {
                if (cb < 512) {
#pragma unroll
                    for (int q = 0; q < 4; ++q)
                        Cb[(long)(rb + l4 * 4 + q) * 512 + cb] = f2b(acc[i][j][q] + bv);
                } else {
                    ushort4 o4;
                    o4.x = f2b(acc[i][j][0] + bv);
                    o4.y = f2b(acc[i][j][1] + bv);
                    o4.z = f2b(acc[i][j][2] + bv);
                    o4.w = f2b(acc[i][j][3] + bv);
                    *(ushort4*)(Cb2 + (long)(cb - 512) * NN + rb + l4 * 4) = o4;
                }
            } else if (FLAGS & 8) {
                ushort4 o4;
                o4.x = f2b(acc[i][j][0] + bv);
                o4.y = f2b(acc[i][j][1] + bv);
                o4.z = f2b(acc[i][j][2] + bv);
                o4.w = f2b(acc[i][j][3] + bv);
                *(ushort4*)(Cb + (long)cb * ldc + rb + l4 * 4) = o4;
            } else {
#pragma unroll
                for (int q = 0; q < 4; ++q) {
                    int r = rb + l4 * 4 + q;
                    float v = acc[i][j][q] + bv;
                    if (FLAGS & 4) v = fmaxf(v, 0.f);
                    if (FLAGS & 1) Cf[(long)r * ldc + cb] = v;
                    if (FLAGS & 2) Cb[(long)r * ldc + cb] = f2b(v);
                }
            }
        }
}

// ---------------- fused GEMM + residual + LayerNorm: x = LN(x + A@B^T + bias) ----------------
__global__ __launch_bounds__(256) void k_gemm_ln(
    const ushort* __restrict__ A, int lda,
    const ushort* __restrict__ B, int ldb, int K,
    const float* __restrict__ bias,
    float* __restrict__ x, ushort* __restrict__ xb,
    const float* __restrict__ gam, const float* __restrict__ bet) {
    __shared__ ushort As[16 * 64];    // 2 KB
    __shared__ ushort Bs[256 * 64];   // 32 KB
    __shared__ float red[4][16][2];
    const int tid = threadIdx.x;
    const int w = tid >> 6, l = tid & 63;
    const int l15 = l & 15, l4 = l >> 4;
    const int row0 = blockIdx.x * 16;
    f32x4 acc[4];
#pragma unroll
    for (int j = 0; j < 4; ++j) acc[j] = (f32x4){0.f, 0.f, 0.f, 0.f};
    for (int k0 = 0; k0 < K; k0 += 64) {
        if (tid < 128) {
            int r = tid >> 3, s = tid & 7;
            bf16x8 va = *(const bf16x8*)(A + (long)(row0 + r) * lda + k0 + s * 8);
            *(bf16x8*)&As[r * 64 + ((s ^ (r & 7)) * 8)] = va;
        }
#pragma unroll
        for (int i = 0; i < 8; ++i) {
            int idx = i * 256 + tid;
            int r = idx >> 3, s = idx & 7;
            bf16x8 vb = *(const bf16x8*)(B + (long)r * ldb + k0 + s * 8);
            *(bf16x8*)&Bs[r * 64 + ((s ^ (r & 7)) * 8)] = vb;
        }
        __syncthreads();
#pragma unroll
        for (int kk = 0; kk < 2; ++kk) {
            bf16x8 af = *(const bf16x8*)&As[l15 * 64 + (((kk * 4 + l4) ^ (l15 & 7)) * 8)];
#pragma unroll
            for (int j = 0; j < 4; ++j) {
                int br = w * 64 + j * 16 + l15;
                bf16x8 bfr = *(const bf16x8*)&Bs[br * 64 + (((kk * 4 + l4) ^ (br & 7)) * 8)];
                acc[j] = __builtin_amdgcn_mfma_f32_16x16x32_bf16(af, bfr, acc[j], 0, 0, 0);
            }
        }
        __syncthreads();
    }
    float val[4][4];
#pragma unroll
    for (int j = 0; j < 4; ++j) {
        int c = w * 64 + j * 16 + l15;
        float bv = bias[c];
#pragma unroll
        for (int q = 0; q < 4; ++q) {
            int r = row0 + l4 * 4 + q;
            val[j][q] = acc[j][q] + bv + x[(long)r * DM + c];
        }
    }
    float sum[4], sq[4];
#pragma unroll
    for (int q = 0; q < 4; ++q) {
        sum[q] = (val[0][q] + val[1][q]) + (val[2][q] + val[3][q]);
        sq[q] = (val[0][q] * val[0][q] + val[1][q] * val[1][q]) +
                (val[2][q] * val[2][q] + val[3][q] * val[3][q]);
    }
#pragma unroll
    for (int o = 1; o < 16; o <<= 1)
#pragma unroll
        for (int q = 0; q < 4; ++q) {
            sum[q] += __shfl_xor(sum[q], o);
            sq[q] += __shfl_xor(sq[q], o);
        }
    if (l15 == 0)
#pragma unroll
        for (int q = 0; q < 4; ++q) {
            red[w][l4 * 4 + q][0] = sum[q];
            red[w][l4 * 4 + q][1] = sq[q];
        }
    __syncthreads();
    float mean[4], rs[4];
#pragma unroll
    for (int q = 0; q < 4; ++q) {
        int rl = l4 * 4 + q;
        float ts = (red[0][rl][0] + red[1][rl][0]) + (red[2][rl][0] + red[3][rl][0]);
        float tq = (red[0][rl][1] + red[1][rl][1]) + (red[2][rl][1] + red[3][rl][1]);
        float m = ts * (1.f / 256.f);
        float var = tq * (1.f / 256.f) - m * m;
        mean[q] = m;
        rs[q] = rsqrtf(var + 1e-5f);
    }
#pragma unroll
    for (int j = 0; j < 4; ++j) {
        int c = w * 64 + j * 16 + l15;
        float gv = gam[c], bv = bet[c];
#pragma unroll
        for (int q = 0; q < 4; ++q) {
            int r = row0 + l4 * 4 + q;
            float ov = (val[j][q] - mean[q]) * rs[q] * gv + bv;
            x[(long)r * DM + c] = ov;
            xb[(long)r * DM + c] = f2b(ov);
        }
    }
}

// ---------------- GCN aggregation ----------------
template <int ACT, int B16>
__global__ void k_gcn_agg(const float* __restrict__ msg, const int* __restrict__ sc,
                          const int* __restrict__ csc_row, const float* __restrict__ dinv,
                          const float* __restrict__ bias,
                          float* __restrict__ outf, ushort* __restrict__ outb) {
    int j = blockIdx.x;
    int d = threadIdx.x;
    float acc = 0.f;
    int a = sc[j], b = sc[j + 1];
    for (int i = a; i < b; ++i) {
        int r = csc_row[i];
        acc += dinv[r] * msg[(long)r * DM + d];
    }
    float dj = dinv[j];
    float v = dj * acc + dj * dj * msg[(long)j * DM + d] + bias[d];
    if (ACT) v = fmaxf(v, 0.f);
    if (B16) outb[(long)j * DM + d] = f2b(v);
    else outf[(long)j * DM + d] = v;
}

__global__ void k_concat(const ushort* __restrict__ nfb, const float* __restrict__ g,
                         ushort* __restrict__ xcb) {
    long i = (long)blockIdx.x * 256 + threadIdx.x;
    if (i >= (long)NN * 384) return;
    int r = (int)(i / 384), c = (int)(i % 384);
    xcb[i] = (c < DIN) ? nfb[(long)r * DIN + c] : f2b(g[(long)r * DM + (c - DIN)]);
}

// ---------------- flash attention: K+V staged in LDS (dbuf), counted vmcnt ----------------
// exp2-domain softmax (log2e folded into Q/bias/sigmoids); bias entries prefetched 1 tile ahead
__global__ __launch_bounds__(256, 4) void k_attn(
    const ushort* __restrict__ qkb, const ushort* __restrict__ vT,
    const int* __restrict__ bstart, const uint* __restrict__ entcomb,
    float* __restrict__ opart, float2* __restrict__ ml) {
    __shared__ ushort Klds[2][4096];  // [buf][r*64 + slot*8] linear, src pre-swizzled
    __shared__ ushort Vlds[2][4096];
    __shared__ ushort Pl[4096];       // per-wave 1024: P^T [16 q][64 kv] XOR-swizzled
    const int qb = blockIdx.x, h = blockIdx.y, cz = blockIdx.z;
    const int tid = threadIdx.x, w = tid >> 6, l = tid & 63;
    const int l15 = l & 15, l4 = l >> 4;
    bf16x8 qf[2];
    {
        const ushort* qp = qkb + (long)(qb * 64 + w * 16 + l15) * 512 + h * 64 + l4 * 8;
        qf[0] = *(const bf16x8*)(qp);
        qf[1] = *(const bf16x8*)(qp + 32);
    }
    const ushort* Kb = qkb + 256 + h * 64;          // row stride 512
    const ushort* Vb = vT + (long)(h * 64) * NN;    // row stride NN
    const uint* ec = entcomb + (long)h * NE;
    f32x4 o[4];
#pragma unroll
    for (int f = 0; f < 4; ++f) o[f] = (f32x4){0.f, 0.f, 0.f, 0.f};
    float m_run = -1e30f, l_run = 0.f;
    char* P = (char*)&Pl[w * 1024];
    const int bktW = (qb * 4 + w) * 64;
    const int t0 = cz * TPC;

    auto stage = [&](int b, int t) {
#pragma unroll
        for (int i = 0; i < 2; ++i) {
            int idx = i * 256 + tid;
            int r = idx >> 3, sl = idx & 7;
            gl_lds16(Kb + (long)(t * 64 + r) * 512 + ((sl ^ (r & 7)) * 8),
                     &Klds[b][idx * 8]);
            gl_lds16(Vb + (long)r * NN + t * 64 + ((sl ^ (r & 7)) * 8),
                     &Vlds[b][idx * 8]);
        }
    };

    int bs_c = bstart[bktW + t0], be_c = bstart[bktW + t0 + 1];
    uint epc[4];
#pragma unroll
    for (int j = 0; j < 4; ++j) epc[j] = ec[bs_c + j];  // entcomb padded; over-read safe
    stage(0, t0);
    int cur = 0;
    for (int tt = 0; tt < TPC; ++tt) {
        const int t = t0 + tt;
        asm volatile("s_waitcnt lgkmcnt(0)" ::: "memory");
        __builtin_amdgcn_s_barrier();
        int bs_n = 0, be_n = 0;
        uint epn[4];
        if (tt + 1 < TPC) {
            stage(cur ^ 1, t + 1);
            bs_n = bstart[bktW + t + 1];
            be_n = bstart[bktW + t + 2];
#pragma unroll
            for (int j = 0; j < 4; ++j) epn[j] = ec[bs_n + j];  // prefetch next-tile entries
            asm volatile("s_waitcnt vmcnt(4)" ::: "memory");  // my buf[cur] loads landed
        } else {
#pragma unroll
            for (int j = 0; j < 4; ++j) epn[j] = 0;
            asm volatile("s_waitcnt vmcnt(0)" ::: "memory");
        }
        __builtin_amdgcn_sched_barrier(0);
        __builtin_amdgcn_s_barrier();  // everyone's buf[cur] ready
        __builtin_amdgcn_sched_barrier(0);

        const ushort* Kl = Klds[cur];
        const ushort* Vl = Vlds[cur];
        // ---- S^T = K Q^T (Q pre-scaled by 0.125*log2e) ----
        f32x4 s4[4];
#pragma unroll
        for (int f = 0; f < 4; ++f) {
            int kc = f * 16 + l15;
            bf16x8 k0 = *(const bf16x8*)&Kl[kc * 64 + ((l4 ^ (kc & 7)) * 8)];
            bf16x8 k1 = *(const bf16x8*)&Kl[kc * 64 + (((4 + l4) ^ (kc & 7)) * 8)];
            f32x4 a = (f32x4){0.f, 0.f, 0.f, 0.f};
            a = __builtin_amdgcn_mfma_f32_16x16x32_bf16(k0, qf[0], a, 0, 0, 0);
            a = __builtin_amdgcn_mfma_f32_16x16x32_bf16(k1, qf[1], a, 0, 0, 0);
            s4[f] = a;
        }
        // ---- sparse bias: precomputed sigmoid*log2e in high 16 bits (bf16) ----
        auto applyEnt = [&](uint e) {
            int r4 = (e >> 6) & 15, c6 = e & 63;
            if (l15 == r4 && ((c6 >> 2) & 3) == l4) {
                union { uint u; float f; } sv;
                sv.u = e & 0xFFFF0000u;
                float sig = sv.f;
                switch (((c6 >> 4) << 2) | (c6 & 3)) {
                    case 0:  s4[0][0] += sig; break; case 1:  s4[0][1] += sig; break;
                    case 2:  s4[0][2] += sig; break; case 3:  s4[0][3] += sig; break;
                    case 4:  s4[1][0] += sig; break; case 5:  s4[1][1] += sig; break;
                    case 6:  s4[1][2] += sig; break; case 7:  s4[1][3] += sig; break;
                    case 8:  s4[2][0] += sig; break; case 9:  s4[2][1] += sig; break;
                    case 10: s4[2][2] += sig; break; case 11: s4[2][3] += sig; break;
                    case 12: s4[3][0] += sig; break; case 13: s4[3][1] += sig; break;
                    case 14: s4[3][2] += sig; break; case 15: s4[3][3] += sig; break;
                }
            }
        };
        {
            int nb = be_c - bs_c;
#pragma unroll
            for (int j = 0; j < 4; ++j)
                if (j < nb) applyEnt(epc[j]);
            for (int i = bs_c + 4; i < be_c; ++i) applyEnt(ec[i]);
        }
        // ---- online softmax in exp2 domain, defer-max (T13, THR=11.5 bits ~ e^8) ----
        float ma = fmaxf(fmaxf(s4[0][0], s4[0][1]), fmaxf(s4[0][2], s4[0][3]));
        float mb = fmaxf(fmaxf(s4[1][0], s4[1][1]), fmaxf(s4[1][2], s4[1][3]));
        float mc = fmaxf(fmaxf(s4[2][0], s4[2][1]), fmaxf(s4[2][2], s4[2][3]));
        float md = fmaxf(fmaxf(s4[3][0], s4[3][1]), fmaxf(s4[3][2], s4[3][3]));
        float me = fmaxf(fmaxf(ma, mb), fmaxf(mc, md));
        me = fmaxf(me, __shfl_xor(me, 16));
        me = fmaxf(me, __shfl_xor(me, 32));
        if (!__all(me <= m_run + 11.5f)) {
            float mn = fmaxf(m_run, me);
            float fac = exp2f(m_run - mn);
            m_run = mn;
            l_run *= fac;
#pragma unroll
            for (int f = 0; f < 4; ++f)
#pragma unroll
                for (int r = 0; r < 4; ++r) o[f][r] *= fac;
        }
        float rp[4];
#pragma unroll
        for (int f = 0; f < 4; ++f) {
            float p0 = exp2f(s4[f][0] - m_run);
            float p1 = exp2f(s4[f][1] - m_run);
            float p2 = exp2f(s4[f][2] - m_run);
            float p3 = exp2f(s4[f][3] - m_run);
            s4[f][0] = p0; s4[f][1] = p1; s4[f][2] = p2; s4[f][3] = p3;
            rp[f] = (p0 + p1) + (p2 + p3);
        }
        float rsum = (rp[0] + rp[1]) + (rp[2] + rp[3]);
        rsum += __shfl_xor(rsum, 16);
        rsum += __shfl_xor(rsum, 32);
        l_run += rsum;
        // ---- P^T -> per-wave LDS (bf16 pairs, slot-XOR swizzled) ----
#pragma unroll
        for (int f = 0; f < 4; ++f)
#pragma unroll
            for (int p = 0; p < 2; ++p) {
                uint u = cvt_pk_bf16(s4[f][2 * p], s4[f][2 * p + 1]);
                int slot = f * 2 + (l4 >> 1);
                int byte = l15 * 128 + ((slot ^ (l15 & 7)) << 4) + (l4 & 1) * 8 + p * 4;
                *(uint*)(P + byte) = u;
            }
        asm volatile("s_waitcnt lgkmcnt(0)" ::: "memory");
        __builtin_amdgcn_sched_barrier(0);
        // ---- O^T += V^T P^T ----
#pragma unroll
        for (int ks = 0; ks < 2; ++ks) {
            bf16x8 pb = *(const bf16x8*)(P + l15 * 128 + (((ks * 4 + l4) ^ (l15 & 7)) << 4));
#pragma unroll
            for (int fd = 0; fd < 4; ++fd) {
                int d = fd * 16 + l15;
                bf16x8 vfr = *(const bf16x8*)&Vl[d * 64 + (((ks * 4 + l4) ^ (d & 7)) * 8)];
                o[fd] = __builtin_amdgcn_mfma_f32_16x16x32_bf16(vfr, pb, o[fd], 0, 0, 0);
            }
        }
        bs_c = bs_n; be_c = be_n;
#pragma unroll
        for (int j = 0; j < 4; ++j) epc[j] = epn[j];
        cur ^= 1;
    }
    // ---- write partials: O^T lane q = l15, d = fd*16 + l4*4 + r ----
    long base = (((long)cz * NH + h) * NN + qb * 64 + w * 16 + l15) * 64;
#pragma unroll
    for (int fd = 0; fd < 4; ++fd)
#pragma unroll
        for (int r = 0; r < 4; ++r)
            opart[base + fd * 16 + l4 * 4 + r] = o[fd][r];
    if (l4 == 0)
        ml[((long)cz * NH + h) * NN + qb * 64 + w * 16 + l15] = make_float2(m_run, l_run);
}

// merge NCH chunk partials -> attnOb (bf16); m values are in log2 domain
__global__ __launch_bounds__(256) void k_comb(const float* __restrict__ opart,
                                              const float2* __restrict__ ml,
                                              ushort* __restrict__ attnOb) {
    int t = blockIdx.x * 256 + threadIdx.x;  // NN*NH*64 total
    int d = t & 63;
    int r = (t >> 6) & (NN - 1);
    int h = t >> 18;
    float2 mls[NCH];
    float M = -1e30f;
#pragma unroll
    for (int c = 0; c < NCH; ++c) {
        mls[c] = ml[((long)c * NH + h) * NN + r];
        M = fmaxf(M, mls[c].x);
    }
    float s = 0.f, ov = 0.f;
#pragma unroll
    for (int c = 0; c < NCH; ++c) {
        float e = exp2f(mls[c].x - M);
        s += mls[c].y * e;
        ov += opart[(((long)c * NH + h) * NN + r) * 64 + d] * e;
    }
    attnOb[(long)r * DM + h * 64 + d] = f2b(ov / s);
}

// ---------------- output ----------------

__global__ void k_out(const float* __restrict__ x, const float* __restrict__ w,
                      const float* __restrict__ b, float* __restrict__ out) {
    int row = blockIdx.x;
    int lane = threadIdx.x;
    float s = 0.f;
#pragma unroll
    for (int i = 0; i < 4; ++i) s += x[(long)row * DM + lane + 64 * i] * w[lane + 64 * i];
#pragma unroll
    for (int o = 1; o < 64; o <<= 1) s += __shfl_xor(s, o);
    if (lane == 0) out[row] = 1.f / (1.f + expf(-(s + b[0])));
}

__global__ void k_sentinel(float* out, int n) {
    int i = blockIdx.x * 256 + threadIdx.x;
    if (i < n) out[i] = 1.0e9f;
}

// ---------------- host ----------------

extern "C" void kernel_launch(void* const* d_in, const int* in_sizes, int n_in,
                              void* d_out, int out_size, void* d_ws, size_t ws_size,
                              hipStream_t stream) {
    const float* nf = (const float*)d_in[0];
    const int* ei = (const int*)d_in[1];
    const int* erow = ei;
    const int* ecol = ei + NE;
    const float* gcn1_w = (const float*)d_in[2];
    const float* gcn1_b = (const float*)d_in[3];
    const float* gcn2_w = (const float*)d_in[4];
    const float* gcn2_b = (const float*)d_in[5];
    const float* edge_w = (const float*)d_in[6];
    const float* edge_b = (const float*)d_in[7];
    const float* proj_w = (const float*)d_in[8];
    const float* proj_b = (const float*)d_in[9];
    const float* wqkv = (const float*)d_in[10];
    const float* bqkv = (const float*)d_in[11];
    const float* wo = (const float*)d_in[12];
    const float* bo = (const float*)d_in[13];
    const float* ffn_w1 = (const float*)d_in[14];
    const float* ffn_b1 = (const float*)d_in[15];
    const float* ffn_w2 = (const float*)d_in[16];
    const float* ffn_b2 = (const float*)d_in[17];
    const float* ln1_g = (const float*)d_in[18];
    const float* ln1_b = (const float*)d_in[19];
    const float* ln2_g = (const float*)d_in[20];
    const float* ln2_b = (const float*)d_in[21];
    const float* out_w = (const float*)d_in[22];
    const float* out_b = (const float*)d_in[23];
    float* out = (float*)d_out;

    char* wp = (char*)d_ws;
    size_t off = 0;
    auto alloc = [&](size_t bytes) -> void* {
        void* p = wp + off;
        off = (off + bytes + 255) & ~(size_t)255;
        return p;
    };
    // big union block (16 MB): msg (GCN) / opart (attn) / ffnHb (ffn)
    char* big = (char*)alloc((size_t)NCH * NH * NN * 64 * 4);
    float* msg = (float*)big;
    float* opart = (float*)big;
    ushort* ffnHb = (ushort*)big;  // 8 MB
    float* x = (float*)alloc((size_t)NN * DM * 4);
    ushort* xb = (ushort*)alloc((size_t)NN * DM * 2);
    ushort* xcb = (ushort*)alloc((size_t)NN * 384 * 2);
    ushort* hb = (ushort*)alloc((size_t)NN * DM * 2);
    float* g = (float*)alloc((size_t)NN * DM * 4);
    ushort* qkb = (ushort*)alloc((size_t)NN * 512 * 2);
    ushort* vT = (ushort*)alloc((size_t)DM * NN * 2);
    ushort* attnOb = (ushort*)alloc((size_t)NN * DM * 2);
    float2* ml = (float2*)alloc((size_t)NCH * NH * NN * 8);
    ushort* nfb = (ushort*)alloc((size_t)NN * DIN * 2);
    ushort* wqkvb = (ushort*)alloc((size_t)NL * 768 * DM * 2);
    ushort* wob = (ushort*)alloc((size_t)NL * DM * DM * 2);
    ushort* f1b = (ushort*)alloc((size_t)NL * 1024 * DM * 2);
    ushort* f2bw = (ushort*)alloc((size_t)NL * DM * 1024 * 2);
    ushort* g1b = (ushort*)alloc((size_t)DM * DIN * 2);
    ushort* g2b = (ushort*)alloc((size_t)DM * DM * 2);
    ushort* pjb = (ushort*)alloc((size_t)DM * 384 * 2);
    float* bq2 = (float*)alloc((size_t)NL * 768 * 4);
    uint* bitmap = (uint*)alloc((size_t)NN * NN / 8);
    unsigned char* flag = (unsigned char*)alloc(NE);
    int* cnt_c = (int*)alloc((size_t)NN * 4);
    int* bcnt = (int*)alloc((size_t)NBKT * 4);
    int* sc = (int*)alloc((size_t)(NN + 1) * 4);
    int* bstart = (int*)alloc((size_t)(NBKT + 1) * 4);
    int* fc = (int*)alloc((size_t)NN * 4);
    int* bfill = (int*)alloc((size_t)NBKT * 4);
    int* csc_row = (int*)alloc((size_t)NE * 4);
    uint* entcomb = (uint*)alloc(((size_t)NH * NE + 16) * 4);  // +16 pad for prefetch over-read
    float* dinv = (float*)alloc((size_t)NN * 4);

    if (off > ws_size) {
        k_sentinel<<<(out_size + 255) / 256, 256, 0, stream>>>(out, out_size);
        return;
    }

    // ---- preprocessing ----
    hipMemsetAsync(bitmap, 0, (size_t)NN * NN / 8, stream);
    hipMemsetAsync(cnt_c, 0, NN * 4, stream);
    hipMemsetAsync(bcnt, 0, NBKT * 4, stream);
    hipMemsetAsync(fc, 0, NN * 4, stream);
    hipMemsetAsync(bfill, 0, NBKT * 4, stream);
    k_edge1<<<NE / 256, 256, 0, stream>>>(erow, ecol, bitmap, cnt_c, bcnt, flag);
    k_scan<NN><<<1, 256, 0, stream>>>(cnt_c, sc);
    k_scan<NBKT><<<1, 256, 0, stream>>>(bcnt, bstart);
    k_edge2<<<NE / 256, 256, 0, stream>>>(erow, ecol, flag, sc, fc, csc_row, bstart, bfill,
                                          entcomb, edge_w, edge_b);
    k_dinv<<<NN / 256, 256, 0, stream>>>(cnt_c, dinv);

    // ---- weight/input conversion ----
    CvtP cp;
    cp.s[0] = nf;      cp.d[0] = nfb;   cp.n[0] = NN * DIN;
    cp.s[1] = wqkv;    cp.d[1] = wqkvb; cp.n[1] = NL * 768 * DM;
    cp.s[2] = wo;      cp.d[2] = wob;   cp.n[2] = NL * DM * DM;
    cp.s[3] = ffn_w1;  cp.d[3] = f1b;   cp.n[3] = NL * 1024 * DM;
    cp.s[4] = ffn_w2;  cp.d[4] = f2bw;  cp.n[4] = NL * DM * 1024;
    cp.s[5] = gcn1_w;  cp.d[5] = g1b;   cp.n[5] = DM * DIN;
    cp.s[6] = gcn2_w;  cp.d[6] = g2b;   cp.n[6] = DM * DM;
    cp.s[7] = proj_w;  cp.d[7] = pjb;   cp.n[7] = DM * 384;
    k_cvt<<<dim3(768, 8), 256, 0, stream>>>(cp);
    k_scaleb<<<(NL * 768 + 255) / 256, 256, 0, stream>>>(bqkv, bq2);

    // ---- GCN ----
    k_gemm_b<1><<<dim3(DM / 128, NN / 128), 256, 0, stream>>>(
        nfb, DIN, g1b, DIN, msg, nullptr, nullptr, DM, DIN, nullptr);
    k_gcn_agg<1, 1><<<NN, DM, 0, stream>>>(msg, sc, csc_row, dinv, gcn1_b, nullptr, hb);
    k_gemm_b<1><<<dim3(DM / 128, NN / 128), 256, 0, stream>>>(
        hb, DM, g2b, DM, msg, nullptr, nullptr, DM, DM, nullptr);
    k_gcn_agg<0, 0><<<NN, DM, 0, stream>>>(msg, sc, csc_row, dinv, gcn2_b, g, nullptr);
    // ---- proj ----
    k_concat<<<(NN * 384 + 255) / 256, 256, 0, stream>>>(nfb, g, xcb);
    k_gemm_b<3><<<dim3(DM / 128, NN / 128), 256, 0, stream>>>(
        xcb, 384, pjb, 384, x, xb, nullptr, DM, 384, proj_b);

    for (int l = 0; l < NL; ++l) {
        // merged qkv: q,k -> qkb [n][512] (q pre-scaled); v -> vT [256][NN] transposed
        k_gemm_b<18><<<dim3(768 / 128, NN / 128), 256, 0, stream>>>(
            xb, DM, wqkvb + (long)l * 768 * DM, DM, nullptr, qkb, vT, 512, DM,
            bq2 + (long)l * 768);
        k_attn<<<dim3(NN / 64, NH, NCH), 256, 0, stream>>>(
            qkb, vT, bstart, entcomb, opart, ml);
        k_comb<<<NN * NH * 64 / 256, 256, 0, stream>>>(opart, ml, attnOb);
        // fused: x = LN1(x + attnO @ wo^T + bo)
        k_gemm_ln<<<NN / 16, 256, 0, stream>>>(
            attnOb, DM, wob + (long)l * DM * DM, DM, DM, bo + (long)l * DM,
            x, xb, ln1_g + (long)l * DM, ln1_b + (long)l * DM);
        k_gemm_b<6><<<dim3(1024 / 128, NN / 128), 256, 0, stream>>>(
            xb, DM, f1b + (long)l * 1024 * DM, DM, nullptr, ffnHb, nullptr, 1024, DM,
            ffn_b1 + (long)l * 1024);
        // fused: x = LN2(x + ffnH @ w2^T + b2)
        k_gemm_ln<<<NN / 16, 256, 0, stream>>>(
            ffnHb, 1024, f2bw + (long)l * DM * 1024, 1024, 1024, ffn_b2 + (long)l * DM,
            x, xb, ln2_g + (long)l * DM, ln2_b + (long)l * DM);
    }
    k_out<<<NN, 64, 0, stream>>>(x, out_w, out_b, out);
}

// Round 12
// 478.322 us; speedup vs baseline: 1.0344x; 1.0344x over previous
//
#include <hip/hip_runtime.h>
#include <math.h>

#define NN 4096
#define NE 65536
#define DIN 128
#define DM 256
#define NH 4
#define NL 3
#define NCH 4
#define TPC (NN / 64 / NCH)  // 16 KV tiles per chunk
#define NBKT 16384           // bias buckets: (r>>4) * 64 + (c>>6)

typedef __attribute__((ext_vector_type(8))) short bf16x8;
typedef __attribute__((ext_vector_type(4))) float f32x4;

__device__ inline ushort f2b(float f) {
    union { float f; uint u; } v; v.f = f;
    uint r = v.u + 0x7fffu + ((v.u >> 16) & 1u);
    return (ushort)(r >> 16);
}

__device__ inline uint cvt_pk_bf16(float lo, float hi) {
    uint r;
    asm("v_cvt_pk_bf16_f32 %0, %1, %2" : "=v"(r) : "v"(lo), "v"(hi));
    return r;
}

__device__ inline void gl_lds16(const ushort* g, ushort* l) {
    __builtin_amdgcn_global_load_lds(
        (const __attribute__((address_space(1))) void*)g,
        (__attribute__((address_space(3))) void*)l, 16, 0, 0);
}

// ---------------- preprocessing ----------------

__global__ void k_edge1(const int* __restrict__ row, const int* __restrict__ col,
                        uint* __restrict__ bitmap, int* __restrict__ cnt_c,
                        int* __restrict__ bcnt, unsigned char* __restrict__ flag) {
    int e = blockIdx.x * 256 + threadIdx.x;
    if (e >= NE) return;
    int r = row[e], c = col[e];
    atomicAdd(&cnt_c[c], 1);
    uint idx = (uint)r * 4096u + (uint)c;
    uint m = 1u << (idx & 31);
    uint old = atomicOr(&bitmap[idx >> 5], m);
    int isnew = (old & m) ? 0 : 1;
    flag[e] = (unsigned char)isnew;
    if (isnew) atomicAdd(&bcnt[(r >> 4) * 64 + (c >> 6)], 1);
}

// fills CSC and per-(wave,tile) bias entries with PRECOMPUTED per-head sigmoids
__global__ void k_edge2(const int* __restrict__ row, const int* __restrict__ col,
                        const unsigned char* __restrict__ flag,
                        const int* __restrict__ sc, int* __restrict__ fc, int* __restrict__ csc_row,
                        const int* __restrict__ bstart, int* __restrict__ bfill,
                        uint* __restrict__ entcomb,
                        const float* __restrict__ ew, const float* __restrict__ eb) {
    int e = blockIdx.x * 256 + threadIdx.x;
    if (e >= NE) return;
    int r = row[e], c = col[e];
    csc_row[sc[c] + atomicAdd(&fc[c], 1)] = r;
    if (flag[e]) {
        int key = (r >> 4) * 64 + (c >> 6);
        int pos = bstart[key] + atomicAdd(&bfill[key], 1);
        uint idx = (uint)(((r & 15) << 6) | (c & 63));
        float fr = (float)r, fc2 = (float)c;
#pragma unroll
        for (int h = 0; h < NH; ++h) {
            float arg = ew[h * 3 + 0] * fr + ew[h * 3 + 1] * fc2 + ew[h * 3 + 2] + eb[h];
            float sig = 1.f / (1.f + __expf(-arg));
            entcomb[(long)h * NE + pos] = idx | ((uint)f2b(sig) << 16);
        }
    }
}

// exclusive scan of N ints -> start[0..N]
template <int N>
__global__ void k_scan(const int* __restrict__ cnt, int* __restrict__ start) {
    __shared__ int part[256];
    const int C = N / 256;
    int t = threadIdx.x;
    int s = 0;
    for (int i = 0; i < C; ++i) s += cnt[t * C + i];
    part[t] = s;
    __syncthreads();
    if (t == 0) {
        int acc = 0;
        for (int i = 0; i < 256; ++i) { int v = part[i]; part[i] = acc; acc += v; }
        start[N] = acc;
    }
    __syncthreads();
    int acc = part[t];
    for (int i = 0; i < C; ++i) { start[t * C + i] = acc; acc += cnt[t * C + i]; }
}

__global__ void k_dinv(const int* __restrict__ cnt_c, float* __restrict__ dinv) {
    int i = blockIdx.x * 256 + threadIdx.x;
    if (i < NN) dinv[i] = 1.0f / sqrtf((float)(cnt_c[i] + 1));
}

// ---------------- f32 -> bf16 batch convert (y==1: scale q-rows by 0.125) ----------------
struct CvtP { const float* s[8]; ushort* d[8]; int n[8]; };
__global__ void k_cvt(CvtP p) {
    int y = blockIdx.y;
    int base = (blockIdx.x * 256 + threadIdx.x) * 4;
    if (base >= p.n[y]) return;
    float4 v = *(const float4*)(p.s[y] + base);
    float sc = 1.f;
    if (y == 1 && ((base >> 8) % 768) < 256) sc = 0.125f;  // fold softmax 1/sqrt(64) into Q
    ushort4 o;
    o.x = f2b(v.x * sc); o.y = f2b(v.y * sc); o.z = f2b(v.z * sc); o.w = f2b(v.w * sc);
    *(ushort4*)(p.d[y] + base) = o;
}

__global__ void k_scaleb(const float* __restrict__ b, float* __restrict__ o) {
    int i = blockIdx.x * 256 + threadIdx.x;
    if (i < NL * 768) o[i] = b[i] * (((i % 768) < 256) ? 0.125f : 1.f);
}

// ---------------- bf16 MFMA GEMM: C = act(A @ B^T + bias) ----------------
// Staging via global_load_lds (pre-swizzled source, linear LDS dest).
// FLAGS: 1 = f32 Cf, 2 = bf16 Cb, 4 = relu, 8 = bf16 TRANSPOSED (Cb[c*ldc+r]),
// 16 = qkv-split: col<512 -> Cb[r*512+c], col>=512 -> Cb2[(c-512)*NN + r] transposed
template <int FLAGS>
__global__ __launch_bounds__(256) void k_gemm_b(
    const ushort* __restrict__ A, int lda,
    const ushort* __restrict__ B, int ldb,
    float* __restrict__ Cf, ushort* __restrict__ Cb, ushort* __restrict__ Cb2, int ldc,
    int K, const float* __restrict__ bias) {
    __shared__ ushort As[128 * 64];
    __shared__ ushort Bs[128 * 64];
    const int tid = threadIdx.x;
    const int w = tid >> 6, l = tid & 63;
    const int l15 = l & 15, l4 = l >> 4;
    const int row0 = blockIdx.y * 128, col0 = blockIdx.x * 128;
    const int wm = (w >> 1) * 64, wn = (w & 1) * 64;
    f32x4 acc[4][4];
#pragma unroll
    for (int i = 0; i < 4; ++i)
#pragma unroll
        for (int j = 0; j < 4; ++j) acc[i][j] = (f32x4){0.f, 0.f, 0.f, 0.f};
    for (int k0 = 0; k0 < K; k0 += 64) {
#pragma unroll
        for (int i = 0; i < 4; ++i) {
            int ci = tid + 256 * i;
            int r = ci >> 3, s = ci & 7;
            gl_lds16(A + (long)(row0 + r) * lda + k0 + ((s ^ (r & 7)) * 8), &As[ci * 8]);
            gl_lds16(B + (long)(col0 + r) * ldb + k0 + ((s ^ (r & 7)) * 8), &Bs[ci * 8]);
        }
        __syncthreads();
#pragma unroll
        for (int kk = 0; kk < 2; ++kk) {
            bf16x8 af[4], bfr[4];
#pragma unroll
            for (int i = 0; i < 4; ++i) {
                int ar = wm + i * 16 + l15;
                af[i] = *(const bf16x8*)&As[ar * 64 + (((kk * 4 + l4) ^ (ar & 7)) * 8)];
                int br = wn + i * 16 + l15;
                bfr[i] = *(const bf16x8*)&Bs[br * 64 + (((kk * 4 + l4) ^ (br & 7)) * 8)];
            }
#pragma unroll
            for (int i = 0; i < 4; ++i)
#pragma unroll
                for (int j = 0; j < 4; ++j)
                    acc[i][j] = __builtin_amdgcn_mfma_f32_16x16x32_bf16(af[i], bfr[j], acc[i][j], 0, 0, 0);
        }
        __syncthreads();
    }
#pragma unroll
    for (int i = 0; i < 4; ++i)
#pragma unroll
        for (int j = 0; j < 4; ++j) {
            int rb = row0 + wm + i * 16;
            int cb = col0 + wn + j * 16 + l15;
            float bv = bias ? bias[cb] : 0.f;
            if (FLAGS & 16) {
                if (cb < 512) {
#pragma unroll
                    for (int q = 0; q < 4; ++q)
                        Cb[(long)(rb + l4 * 4 + q) * 512 + cb] = f2b(acc[i][j][q] + bv);
                } else {
                    ushort4 o4;
                    o4.x = f2b(acc[i][j][0] + bv);
                    o4.y = f2b(acc[i][j][1] + bv);
                    o4.z = f2b(acc[i][j][2] + bv);
                    o4.w = f2b(acc[i][j][3] + bv);
                    *(ushort4*)(Cb2 + (long)(cb - 512) * NN + rb + l4 * 4) = o4;
                }
            } else if (FLAGS & 8) {
                ushort4 o4;
                o4.x = f2b(acc[i][j][0] + bv);
                o4.y = f2b(acc[i][j][1] + bv);
                o4.z = f2b(acc[i][j][2] + bv);
                o4.w = f2b(acc[i][j][3] + bv);
                *(ushort4*)(Cb + (long)cb * ldc + rb + l4 * 4) = o4;
            } else {
#pragma unroll
                for (int q = 0; q < 4; ++q) {
                    int r = rb + l4 * 4 + q;
                    float v = acc[i][j][q] + bv;
                    if (FLAGS & 4) v = fmaxf(v, 0.f);
                    if (FLAGS & 1) Cf[(long)r * ldc + cb] = v;
                    if (FLAGS & 2) Cb[(long)r * ldc + cb] = f2b(v);
                }
            }
        }
}

// ---------------- fused GEMM + residual + LayerNorm: x = LN(x + A@B^T + bias) ----------------
__global__ __launch_bounds__(256) void k_gemm_ln(
    const ushort* __restrict__ A, int lda,
    const ushort* __restrict__ B, int ldb, int K,
    const float* __restrict__ bias,
    float* __restrict__ x, ushort* __restrict__ xb,
    const float* __restrict__ gam, const float* __restrict__ bet) {
    __shared__ ushort As[16 * 64];    // 2 KB
    __shared__ ushort Bs[256 * 64];   // 32 KB
    __shared__ float red[4][16][2];
    const int tid = threadIdx.x;
    const int w = tid >> 6, l = tid & 63;
    const int l15 = l & 15, l4 = l >> 4;
    const int row0 = blockIdx.x * 16;
    f32x4 acc[4];
#pragma unroll
    for (int j = 0; j < 4; ++j) acc[j] = (f32x4){0.f, 0.f, 0.f, 0.f};
    for (int k0 = 0; k0 < K; k0 += 64) {
        if (tid < 128) {
            int r = tid >> 3, s = tid & 7;
            gl_lds16(A + (long)(row0 + r) * lda + k0 + ((s ^ (r & 7)) * 8), &As[tid * 8]);
        }
#pragma unroll
        for (int i = 0; i < 8; ++i) {
            int idx = i * 256 + tid;
            int r = idx >> 3, s = idx & 7;
            gl_lds16(B + (long)r * ldb + k0 + ((s ^ (r & 7)) * 8), &Bs[idx * 8]);
        }
        __syncthreads();
#pragma unroll
        for (int kk = 0; kk < 2; ++kk) {
            bf16x8 af = *(const bf16x8*)&As[l15 * 64 + (((kk * 4 + l4) ^ (l15 & 7)) * 8)];
#pragma unroll
            for (int j = 0; j < 4; ++j) {
                int br = w * 64 + j * 16 + l15;
                bf16x8 bfr = *(const bf16x8*)&Bs[br * 64 + (((kk * 4 + l4) ^ (br & 7)) * 8)];
                acc[j] = __builtin_amdgcn_mfma_f32_16x16x32_bf16(af, bfr, acc[j], 0, 0, 0);
            }
        }
        __syncthreads();
    }
    float val[4][4];
#pragma unroll
    for (int j = 0; j < 4; ++j) {
        int c = w * 64 + j * 16 + l15;
        float bv = bias[c];
#pragma unroll
        for (int q = 0; q < 4; ++q) {
            int r = row0 + l4 * 4 + q;
            val[j][q] = acc[j][q] + bv + x[(long)r * DM + c];
        }
    }
    float sum[4], sq[4];
#pragma unroll
    for (int q = 0; q < 4; ++q) {
        sum[q] = (val[0][q] + val[1][q]) + (val[2][q] + val[3][q]);
        sq[q] = (val[0][q] * val[0][q] + val[1][q] * val[1][q]) +
                (val[2][q] * val[2][q] + val[3][q] * val[3][q]);
    }
#pragma unroll
    for (int o = 1; o < 16; o <<= 1)
#pragma unroll
        for (int q = 0; q < 4; ++q) {
            sum[q] += __shfl_xor(sum[q], o);
            sq[q] += __shfl_xor(sq[q], o);
        }
    if (l15 == 0)
#pragma unroll
        for (int q = 0; q < 4; ++q) {
            red[w][l4 * 4 + q][0] = sum[q];
            red[w][l4 * 4 + q][1] = sq[q];
        }
    __syncthreads();
    float mean[4], rs[4];
#pragma unroll
    for (int q = 0; q < 4; ++q) {
        int rl = l4 * 4 + q;
        float ts = (red[0][rl][0] + red[1][rl][0]) + (red[2][rl][0] + red[3][rl][0]);
        float tq = (red[0][rl][1] + red[1][rl][1]) + (red[2][rl][1] + red[3][rl][1]);
        float m = ts * (1.f / 256.f);
        float var = tq * (1.f / 256.f) - m * m;
        mean[q] = m;
        rs[q] = rsqrtf(var + 1e-5f);
    }
#pragma unroll
    for (int j = 0; j < 4; ++j) {
        int c = w * 64 + j * 16 + l15;
        float gv = gam[c], bv = bet[c];
#pragma unroll
        for (int q = 0; q < 4; ++q) {
            int r = row0 + l4 * 4 + q;
            float ov = (val[j][q] - mean[q]) * rs[q] * gv + bv;
            x[(long)r * DM + c] = ov;
            xb[(long)r * DM + c] = f2b(ov);
        }
    }
}

// ---------------- GCN aggregation ----------------
template <int ACT, int B16>
__global__ void k_gcn_agg(const float* __restrict__ msg, const int* __restrict__ sc,
                          const int* __restrict__ csc_row, const float* __restrict__ dinv,
                          const float* __restrict__ bias,
                          float* __restrict__ outf, ushort* __restrict__ outb) {
    int j = blockIdx.x;
    int d = threadIdx.x;
    float acc = 0.f;
    int a = sc[j], b = sc[j + 1];
    for (int i = a; i < b; ++i) {
        int r = csc_row[i];
        acc += dinv[r] * msg[(long)r * DM + d];
    }
    float dj = dinv[j];
    float v = dj * acc + dj * dj * msg[(long)j * DM + d] + bias[d];
    if (ACT) v = fmaxf(v, 0.f);
    if (B16) outb[(long)j * DM + d] = f2b(v);
    else outf[(long)j * DM + d] = v;
}

__global__ void k_concat(const ushort* __restrict__ nfb, const float* __restrict__ g,
                         ushort* __restrict__ xcb) {
    long i = (long)blockIdx.x * 256 + threadIdx.x;
    if (i >= (long)NN * 384) return;
    int r = (int)(i / 384), c = (int)(i % 384);
    xcb[i] = (c < DIN) ? nfb[(long)r * DIN + c] : f2b(g[(long)r * DM + (c - DIN)]);
}

// ---------------- flash attention: K+V staged in LDS (dbuf), counted vmcnt ----------------
// (R10-exact 66.4 us config: e-domain softmax, simple bias loop, precomputed sigmoids)
__global__ __launch_bounds__(256, 4) void k_attn(
    const ushort* __restrict__ qkb, const ushort* __restrict__ vT,
    const int* __restrict__ bstart, const uint* __restrict__ entcomb,
    float* __restrict__ opart, float2* __restrict__ ml) {
    __shared__ ushort Klds[2][4096];  // [buf][r*64 + slot*8] linear, src pre-swizzled
    __shared__ ushort Vlds[2][4096];
    __shared__ ushort Pl[4096];       // per-wave 1024: P^T [16 q][64 kv] XOR-swizzled
    const int qb = blockIdx.x, h = blockIdx.y, cz = blockIdx.z;
    const int tid = threadIdx.x, w = tid >> 6, l = tid & 63;
    const int l15 = l & 15, l4 = l >> 4;
    bf16x8 qf[2];
    {
        const ushort* qp = qkb + (long)(qb * 64 + w * 16 + l15) * 512 + h * 64 + l4 * 8;
        qf[0] = *(const bf16x8*)(qp);
        qf[1] = *(const bf16x8*)(qp + 32);
    }
    const ushort* Kb = qkb + 256 + h * 64;          // row stride 512
    const ushort* Vb = vT + (long)(h * 64) * NN;    // row stride NN
    const uint* ec = entcomb + (long)h * NE;
    f32x4 o[4];
#pragma unroll
    for (int f = 0; f < 4; ++f) o[f] = (f32x4){0.f, 0.f, 0.f, 0.f};
    float m_run = -1e30f, l_run = 0.f;
    char* P = (char*)&Pl[w * 1024];
    const int bktW = (qb * 4 + w) * 64;
    const int t0 = cz * TPC;

    auto stage = [&](int b, int t) {
#pragma unroll
        for (int i = 0; i < 2; ++i) {
            int idx = i * 256 + tid;
            int r = idx >> 3, sl = idx & 7;
            gl_lds16(Kb + (long)(t * 64 + r) * 512 + ((sl ^ (r & 7)) * 8),
                     &Klds[b][idx * 8]);
            gl_lds16(Vb + (long)r * NN + t * 64 + ((sl ^ (r & 7)) * 8),
                     &Vlds[b][idx * 8]);
        }
    };

    int bs_c = bstart[bktW + t0], be_c = bstart[bktW + t0 + 1];
    stage(0, t0);
    int cur = 0;
    for (int tt = 0; tt < TPC; ++tt) {
        const int t = t0 + tt;
        asm volatile("s_waitcnt lgkmcnt(0)" ::: "memory");
        __builtin_amdgcn_s_barrier();
        int bs_n = 0, be_n = 0;
        if (tt + 1 < TPC) {
            stage(cur ^ 1, t + 1);
            bs_n = bstart[bktW + t + 1];
            be_n = bstart[bktW + t + 2];
            asm volatile("s_waitcnt vmcnt(4)" ::: "memory");  // my buf[cur] loads landed
        } else {
            asm volatile("s_waitcnt vmcnt(0)" ::: "memory");
        }
        __builtin_amdgcn_sched_barrier(0);
        __builtin_amdgcn_s_barrier();  // everyone's buf[cur] ready
        __builtin_amdgcn_sched_barrier(0);

        const ushort* Kl = Klds[cur];
        const ushort* Vl = Vlds[cur];
        // ---- S^T = K Q^T (Q pre-scaled) ----
        f32x4 s4[4];
#pragma unroll
        for (int f = 0; f < 4; ++f) {
            int kc = f * 16 + l15;
            bf16x8 k0 = *(const bf16x8*)&Kl[kc * 64 + ((l4 ^ (kc & 7)) * 8)];
            bf16x8 k1 = *(const bf16x8*)&Kl[kc * 64 + (((4 + l4) ^ (kc & 7)) * 8)];
            f32x4 a = (f32x4){0.f, 0.f, 0.f, 0.f};
            a = __builtin_amdgcn_mfma_f32_16x16x32_bf16(k0, qf[0], a, 0, 0, 0);
            a = __builtin_amdgcn_mfma_f32_16x16x32_bf16(k1, qf[1], a, 0, 0, 0);
            s4[f] = a;
        }
        // ---- sparse bias: precomputed sigmoid in high 16 bits (bf16) ----
        for (int i = bs_c; i < be_c; ++i) {
            uint e = ec[i];
            int r4 = (e >> 6) & 15, c6 = e & 63;
            if (l15 == r4 && ((c6 >> 2) & 3) == l4) {
                union { uint u; float f; } sv;
                sv.u = e & 0xFFFF0000u;
                float sig = sv.f;
                switch (((c6 >> 4) << 2) | (c6 & 3)) {
                    case 0:  s4[0][0] += sig; break; case 1:  s4[0][1] += sig; break;
                    case 2:  s4[0][2] += sig; break; case 3:  s4[0][3] += sig; break;
                    case 4:  s4[1][0] += sig; break; case 5:  s4[1][1] += sig; break;
                    case 6:  s4[1][2] += sig; break; case 7:  s4[1][3] += sig; break;
                    case 8:  s4[2][0] += sig; break; case 9:  s4[2][1] += sig; break;
                    case 10: s4[2][2] += sig; break; case 11: s4[2][3] += sig; break;
                    case 12: s4[3][0] += sig; break; case 13: s4[3][1] += sig; break;
                    case 14: s4[3][2] += sig; break; case 15: s4[3][3] += sig; break;
                }
            }
        }
        // ---- online softmax with defer-max (T13, THR=8) ----
        float ma = fmaxf(fmaxf(s4[0][0], s4[0][1]), fmaxf(s4[0][2], s4[0][3]));
        float mb = fmaxf(fmaxf(s4[1][0], s4[1][1]), fmaxf(s4[1][2], s4[1][3]));
        float mc = fmaxf(fmaxf(s4[2][0], s4[2][1]), fmaxf(s4[2][2], s4[2][3]));
        float md = fmaxf(fmaxf(s4[3][0], s4[3][1]), fmaxf(s4[3][2], s4[3][3]));
        float me = fmaxf(fmaxf(ma, mb), fmaxf(mc, md));
        me = fmaxf(me, __shfl_xor(me, 16));
        me = fmaxf(me, __shfl_xor(me, 32));
        if (!__all(me <= m_run + 8.f)) {
            float mn = fmaxf(m_run, me);
            float fac = __expf(m_run - mn);
            m_run = mn;
            l_run *= fac;
#pragma unroll
            for (int f = 0; f < 4; ++f)
#pragma unroll
                for (int r = 0; r < 4; ++r) o[f][r] *= fac;
        }
        float rp[4];
#pragma unroll
        for (int f = 0; f < 4; ++f) {
            float p0 = __expf(s4[f][0] - m_run);
            float p1 = __expf(s4[f][1] - m_run);
            float p2 = __expf(s4[f][2] - m_run);
            float p3 = __expf(s4[f][3] - m_run);
            s4[f][0] = p0; s4[f][1] = p1; s4[f][2] = p2; s4[f][3] = p3;
            rp[f] = (p0 + p1) + (p2 + p3);
        }
        float rsum = (rp[0] + rp[1]) + (rp[2] + rp[3]);
        rsum += __shfl_xor(rsum, 16);
        rsum += __shfl_xor(rsum, 32);
        l_run += rsum;
        // ---- P^T -> per-wave LDS (bf16 pairs, slot-XOR swizzled) ----
#pragma unroll
        for (int f = 0; f < 4; ++f)
#pragma unroll
            for (int p = 0; p < 2; ++p) {
                uint u = cvt_pk_bf16(s4[f][2 * p], s4[f][2 * p + 1]);
                int slot = f * 2 + (l4 >> 1);
                int byte = l15 * 128 + ((slot ^ (l15 & 7)) << 4) + (l4 & 1) * 8 + p * 4;
                *(uint*)(P + byte) = u;
            }
        asm volatile("s_waitcnt lgkmcnt(0)" ::: "memory");
        __builtin_amdgcn_sched_barrier(0);
        // ---- O^T += V^T P^T ----
#pragma unroll
        for (int ks = 0; ks < 2; ++ks) {
            bf16x8 pb = *(const bf16x8*)(P + l15 * 128 + (((ks * 4 + l4) ^ (l15 & 7)) << 4));
#pragma unroll
            for (int fd = 0; fd < 4; ++fd) {
                int d = fd * 16 + l15;
                bf16x8 vfr = *(const bf16x8*)&Vl[d * 64 + (((ks * 4 + l4) ^ (d & 7)) * 8)];
                o[fd] = __builtin_amdgcn_mfma_f32_16x16x32_bf16(vfr, pb, o[fd], 0, 0, 0);
            }
        }
        bs_c = bs_n; be_c = be_n;
        cur ^= 1;
    }
    // ---- write partials: O^T lane q = l15, d = fd*16 + l4*4 + r ----
    long base = (((long)cz * NH + h) * NN + qb * 64 + w * 16 + l15) * 64;
#pragma unroll
    for (int fd = 0; fd < 4; ++fd)
#pragma unroll
        for (int r = 0; r < 4; ++r)
            opart[base + fd * 16 + l4 * 4 + r] = o[fd][r];
    if (l4 == 0)
        ml[((long)cz * NH + h) * NN + qb * 64 + w * 16 + l15] = make_float2(m_run, l_run);
}

// merge NCH chunk partials -> attnOb (bf16)
__global__ __launch_bounds__(256) void k_comb(const float* __restrict__ opart,
                                              const float2* __restrict__ ml,
                                              ushort* __restrict__ attnOb) {
    int t = blockIdx.x * 256 + threadIdx.x;  // NN*NH*64 total
    int d = t & 63;
    int r = (t >> 6) & (NN - 1);
    int h = t >> 18;
    float2 mls[NCH];
    float M = -1e30f;
#pragma unroll
    for (int c = 0; c < NCH; ++c) {
        mls[c] = ml[((long)c * NH + h) * NN + r];
        M = fmaxf(M, mls[c].x);
    }
    float s = 0.f, ov = 0.f;
#pragma unroll
    for (int c = 0; c < NCH; ++c) {
        float e = __expf(mls[c].x - M);
        s += mls[c].y * e;
        ov += opart[(((long)c * NH + h) * NN + r) * 64 + d] * e;
    }
    attnOb[(long)r * DM + h * 64 + d] = f2b(ov / s);
}

// ---------------- output ----------------

__global__ void k_out(const float* __restrict__ x, const float* __restrict__ w,
                      const float* __restrict__ b, float* __restrict__ out) {
    int row = blockIdx.x;
    int lane = threadIdx.x;
    float s = 0.f;
#pragma unroll
    for (int i = 0; i < 4; ++i) s += x[(long)row * DM + lane + 64 * i] * w[lane + 64 * i];
#pragma unroll
    for (int o = 1; o < 64; o <<= 1) s += __shfl_xor(s, o);
    if (lane == 0) out[row] = 1.f / (1.f + expf(-(s + b[0])));
}

__global__ void k_sentinel(float* out, int n) {
    int i = blockIdx.x * 256 + threadIdx.x;
    if (i < n) out[i] = 1.0e9f;
}

// ---------------- host ----------------

extern "C" void kernel_launch(void* const* d_in, const int* in_sizes, int n_in,
                              void* d_out, int out_size, void* d_ws, size_t ws_size,
                              hipStream_t stream) {
    const float* nf = (const float*)d_in[0];
    const int* ei = (const int*)d_in[1];
    const int* erow = ei;
    const int* ecol = ei + NE;
    const float* gcn1_w = (const float*)d_in[2];
    const float* gcn1_b = (const float*)d_in[3];
    const float* gcn2_w = (const float*)d_in[4];
    const float* gcn2_b = (const float*)d_in[5];
    const float* edge_w = (const float*)d_in[6];
    const float* edge_b = (const float*)d_in[7];
    const float* proj_w = (const float*)d_in[8];
    const float* proj_b = (const float*)d_in[9];
    const float* wqkv = (const float*)d_in[10];
    const float* bqkv = (const float*)d_in[11];
    const float* wo = (const float*)d_in[12];
    const float* bo = (const float*)d_in[13];
    const float* ffn_w1 = (const float*)d_in[14];
    const float* ffn_b1 = (const float*)d_in[15];
    const float* ffn_w2 = (const float*)d_in[16];
    const float* ffn_b2 = (const float*)d_in[17];
    const float* ln1_g = (const float*)d_in[18];
    const float* ln1_b = (const float*)d_in[19];
    const float* ln2_g = (const float*)d_in[20];
    const float* ln2_b = (const float*)d_in[21];
    const float* out_w = (const float*)d_in[22];
    const float* out_b = (const float*)d_in[23];
    float* out = (float*)d_out;

    char* wp = (char*)d_ws;
    size_t off = 0;
    auto alloc = [&](size_t bytes) -> void* {
        void* p = wp + off;
        off = (off + bytes + 255) & ~(size_t)255;
        return p;
    };
    // big union block (16 MB): msg (GCN) / opart (attn) / ffnHb (ffn)
    char* big = (char*)alloc((size_t)NCH * NH * NN * 64 * 4);
    float* msg = (float*)big;
    float* opart = (float*)big;
    ushort* ffnHb = (ushort*)big;  // 8 MB
    float* x = (float*)alloc((size_t)NN * DM * 4);
    ushort* xb = (ushort*)alloc((size_t)NN * DM * 2);
    ushort* xcb = (ushort*)alloc((size_t)NN * 384 * 2);
    ushort* hb = (ushort*)alloc((size_t)NN * DM * 2);
    float* g = (float*)alloc((size_t)NN * DM * 4);
    ushort* qkb = (ushort*)alloc((size_t)NN * 512 * 2);
    ushort* vT = (ushort*)alloc((size_t)DM * NN * 2);
    ushort* attnOb = (ushort*)alloc((size_t)NN * DM * 2);
    float2* ml = (float2*)alloc((size_t)NCH * NH * NN * 8);
    ushort* nfb = (ushort*)alloc((size_t)NN * DIN * 2);
    ushort* wqkvb = (ushort*)alloc((size_t)NL * 768 * DM * 2);
    ushort* wob = (ushort*)alloc((size_t)NL * DM * DM * 2);
    ushort* f1b = (ushort*)alloc((size_t)NL * 1024 * DM * 2);
    ushort* f2bw = (ushort*)alloc((size_t)NL * DM * 1024 * 2);
    ushort* g1b = (ushort*)alloc((size_t)DM * DIN * 2);
    ushort* g2b = (ushort*)alloc((size_t)DM * DM * 2);
    ushort* pjb = (ushort*)alloc((size_t)DM * 384 * 2);
    float* bq2 = (float*)alloc((size_t)NL * 768 * 4);
    uint* bitmap = (uint*)alloc((size_t)NN * NN / 8);
    unsigned char* flag = (unsigned char*)alloc(NE);
    int* cnt_c = (int*)alloc((size_t)NN * 4);
    int* bcnt = (int*)alloc((size_t)NBKT * 4);
    int* sc = (int*)alloc((size_t)(NN + 1) * 4);
    int* bstart = (int*)alloc((size_t)(NBKT + 1) * 4);
    int* fc = (int*)alloc((size_t)NN * 4);
    int* bfill = (int*)alloc((size_t)NBKT * 4);
    int* csc_row = (int*)alloc((size_t)NE * 4);
    uint* entcomb = (uint*)alloc((size_t)NH * NE * 4);
    float* dinv = (float*)alloc((size_t)NN * 4);

    if (off > ws_size) {
        k_sentinel<<<(out_size + 255) / 256, 256, 0, stream>>>(out, out_size);
        return;
    }

    // ---- preprocessing ----
    hipMemsetAsync(bitmap, 0, (size_t)NN * NN / 8, stream);
    hipMemsetAsync(cnt_c, 0, NN * 4, stream);
    hipMemsetAsync(bcnt, 0, NBKT * 4, stream);
    hipMemsetAsync(fc, 0, NN * 4, stream);
    hipMemsetAsync(bfill, 0, NBKT * 4, stream);
    k_edge1<<<NE / 256, 256, 0, stream>>>(erow, ecol, bitmap, cnt_c, bcnt, flag);
    k_scan<NN><<<1, 256, 0, stream>>>(cnt_c, sc);
    k_scan<NBKT><<<1, 256, 0, stream>>>(bcnt, bstart);
    k_edge2<<<NE / 256, 256, 0, stream>>>(erow, ecol, flag, sc, fc, csc_row, bstart, bfill,
                                          entcomb, edge_w, edge_b);
    k_dinv<<<NN / 256, 256, 0, stream>>>(cnt_c, dinv);

    // ---- weight/input conversion ----
    CvtP cp;
    cp.s[0] = nf;      cp.d[0] = nfb;   cp.n[0] = NN * DIN;
    cp.s[1] = wqkv;    cp.d[1] = wqkvb; cp.n[1] = NL * 768 * DM;
    cp.s[2] = wo;      cp.d[2] = wob;   cp.n[2] = NL * DM * DM;
    cp.s[3] = ffn_w1;  cp.d[3] = f1b;   cp.n[3] = NL * 1024 * DM;
    cp.s[4] = ffn_w2;  cp.d[4] = f2bw;  cp.n[4] = NL * DM * 1024;
    cp.s[5] = gcn1_w;  cp.d[5] = g1b;   cp.n[5] = DM * DIN;
    cp.s[6] = gcn2_w;  cp.d[6] = g2b;   cp.n[6] = DM * DM;
    cp.s[7] = proj_w;  cp.d[7] = pjb;   cp.n[7] = DM * 384;
    k_cvt<<<dim3(768, 8), 256, 0, stream>>>(cp);
    k_scaleb<<<(NL * 768 + 255) / 256, 256, 0, stream>>>(bqkv, bq2);

    // ---- GCN ----
    k_gemm_b<1><<<dim3(DM / 128, NN / 128), 256, 0, stream>>>(
        nfb, DIN, g1b, DIN, msg, nullptr, nullptr, DM, DIN, nullptr);
    k_gcn_agg<1, 1><<<NN, DM, 0, stream>>>(msg, sc, csc_row, dinv, gcn1_b, nullptr, hb);
    k_gemm_b<1><<<dim3(DM / 128, NN / 128), 256, 0, stream>>>(
        hb, DM, g2b, DM, msg, nullptr, nullptr, DM, DM, nullptr);
    k_gcn_agg<0, 0><<<NN, DM, 0, stream>>>(msg, sc, csc_row, dinv, gcn2_b, g, nullptr);
    // ---- proj ----
    k_concat<<<(NN * 384 + 255) / 256, 256, 0, stream>>>(nfb, g, xcb);
    k_gemm_b<3><<<dim3(DM / 128, NN / 128), 256, 0, stream>>>(
        xcb, 384, pjb, 384, x, xb, nullptr, DM, 384, proj_b);

    for (int l = 0; l < NL; ++l) {
        // merged qkv: q,k -> qkb [n][512] (q pre-scaled); v -> vT [256][NN] transposed
        k_gemm_b<18><<<dim3(768 / 128, NN / 128), 256, 0, stream>>>(
            xb, DM, wqkvb + (long)l * 768 * DM, DM, nullptr, qkb, vT, 512, DM,
            bq2 + (long)l * 768);
        k_attn<<<dim3(NN / 64, NH, NCH), 256, 0, stream>>>(
            qkb, vT, bstart, entcomb, opart, ml);
        k_comb<<<NN * NH * 64 / 256, 256, 0, stream>>>(opart, ml, attnOb);
        // fused: x = LN1(x + attnO @ wo^T + bo)
        k_gemm_ln<<<NN / 16, 256, 0, stream>>>(
            attnOb, DM, wob + (long)l * DM * DM, DM, DM, bo + (long)l * DM,
            x, xb, ln1_g + (long)l * DM, ln1_b + (long)l * DM);
        k_gemm_b<6><<<dim3(1024 / 128, NN / 128), 256, 0, stream>>>(
            xb, DM, f1b + (long)l * 1024 * DM, DM, nullptr, ffnHb, nullptr, 1024, DM,
            ffn_b1 + (long)l * 1024);
        // fused: x = LN2(x + ffnH @ w2^T + b2)
        k_gemm_ln<<<NN / 16, 256, 0, stream>>>(
            ffnHb, 1024, f2bw + (long)l * DM * 1024, 1024, 1024, ffn_b2 + (long)l * DM,
            x, xb, ln2_g + (long)l * DM, ln2_b + (long)l * DM);
    }
    k_out<<<NN, 64, 0, stream>>>(x, out_w, out_b, out);
}

// Round 13
// 464.224 us; speedup vs baseline: 1.0658x; 1.0304x over previous
//
#include <hip/hip_runtime.h>
#include <math.h>

#define NN 4096
#define NE 65536
#define DIN 128
#define DM 256
#define NH 4
#define NL 3
#define NCH 4
#define TPC (NN / 64 / NCH)  // 16 KV tiles per chunk
#define NBKT 16384           // bias buckets: (r>>4) * 64 + (c>>6)

typedef __attribute__((ext_vector_type(8))) short bf16x8;
typedef __attribute__((ext_vector_type(4))) float f32x4;

__device__ inline ushort f2b(float f) {
    union { float f; uint u; } v; v.f = f;
    uint r = v.u + 0x7fffu + ((v.u >> 16) & 1u);
    return (ushort)(r >> 16);
}

__device__ inline uint cvt_pk_bf16(float lo, float hi) {
    uint r;
    asm("v_cvt_pk_bf16_f32 %0, %1, %2" : "=v"(r) : "v"(lo), "v"(hi));
    return r;
}

__device__ inline void gl_lds16(const ushort* g, ushort* l) {
    __builtin_amdgcn_global_load_lds(
        (const __attribute__((address_space(1))) void*)g,
        (__attribute__((address_space(3))) void*)l, 16, 0, 0);
}

// ---------------- preprocessing ----------------

__global__ void k_edge1(const int* __restrict__ row, const int* __restrict__ col,
                        uint* __restrict__ bitmap, int* __restrict__ cnt_c,
                        int* __restrict__ bcnt, unsigned char* __restrict__ flag) {
    int e = blockIdx.x * 256 + threadIdx.x;
    if (e >= NE) return;
    int r = row[e], c = col[e];
    atomicAdd(&cnt_c[c], 1);
    uint idx = (uint)r * 4096u + (uint)c;
    uint m = 1u << (idx & 31);
    uint old = atomicOr(&bitmap[idx >> 5], m);
    int isnew = (old & m) ? 0 : 1;
    flag[e] = (unsigned char)isnew;
    if (isnew) atomicAdd(&bcnt[(r >> 4) * 64 + (c >> 6)], 1);
}

// fills CSC and per-(wave,tile) bias entries with PRECOMPUTED per-head sigmoids
__global__ void k_edge2(const int* __restrict__ row, const int* __restrict__ col,
                        const unsigned char* __restrict__ flag,
                        const int* __restrict__ sc, int* __restrict__ fc, int* __restrict__ csc_row,
                        const int* __restrict__ bstart, int* __restrict__ bfill,
                        uint* __restrict__ entcomb,
                        const float* __restrict__ ew, const float* __restrict__ eb) {
    int e = blockIdx.x * 256 + threadIdx.x;
    if (e >= NE) return;
    int r = row[e], c = col[e];
    csc_row[sc[c] + atomicAdd(&fc[c], 1)] = r;
    if (flag[e]) {
        int key = (r >> 4) * 64 + (c >> 6);
        int pos = bstart[key] + atomicAdd(&bfill[key], 1);
        uint idx = (uint)(((r & 15) << 6) | (c & 63));
        float fr = (float)r, fc2 = (float)c;
#pragma unroll
        for (int h = 0; h < NH; ++h) {
            float arg = ew[h * 3 + 0] * fr + ew[h * 3 + 1] * fc2 + ew[h * 3 + 2] + eb[h];
            float sig = 1.f / (1.f + __expf(-arg));
            entcomb[(long)h * NE + pos] = idx | ((uint)f2b(sig) << 16);
        }
    }
}

// exclusive scan of N ints -> start[0..N]
template <int N>
__global__ void k_scan(const int* __restrict__ cnt, int* __restrict__ start) {
    __shared__ int part[256];
    const int C = N / 256;
    int t = threadIdx.x;
    int s = 0;
    for (int i = 0; i < C; ++i) s += cnt[t * C + i];
    part[t] = s;
    __syncthreads();
    if (t == 0) {
        int acc = 0;
        for (int i = 0; i < 256; ++i) { int v = part[i]; part[i] = acc; acc += v; }
        start[N] = acc;
    }
    __syncthreads();
    int acc = part[t];
    for (int i = 0; i < C; ++i) { start[t * C + i] = acc; acc += cnt[t * C + i]; }
}

__global__ void k_dinv(const int* __restrict__ cnt_c, float* __restrict__ dinv) {
    int i = blockIdx.x * 256 + threadIdx.x;
    if (i < NN) dinv[i] = 1.0f / sqrtf((float)(cnt_c[i] + 1));
}

// ---------------- f32 -> bf16 batch convert (y==1: scale q-rows by 0.125) ----------------
struct CvtP { const float* s[8]; ushort* d[8]; int n[8]; };
__global__ void k_cvt(CvtP p) {
    int y = blockIdx.y;
    int base = (blockIdx.x * 256 + threadIdx.x) * 4;
    if (base >= p.n[y]) return;
    float4 v = *(const float4*)(p.s[y] + base);
    float sc = 1.f;
    if (y == 1 && ((base >> 8) % 768) < 256) sc = 0.125f;  // fold softmax 1/sqrt(64) into Q
    ushort4 o;
    o.x = f2b(v.x * sc); o.y = f2b(v.y * sc); o.z = f2b(v.z * sc); o.w = f2b(v.w * sc);
    *(ushort4*)(p.d[y] + base) = o;
}

__global__ void k_scaleb(const float* __restrict__ b, float* __restrict__ o) {
    int i = blockIdx.x * 256 + threadIdx.x;
    if (i < NL * 768) o[i] = b[i] * (((i % 768) < 256) ? 0.125f : 1.f);
}

// ---------------- bf16 MFMA GEMM: C = act(A @ B^T + bias) ----------------
// Staging via global_load_lds (pre-swizzled source, linear LDS dest).
// FLAGS: 1 = f32 Cf, 2 = bf16 Cb, 4 = relu, 8 = bf16 TRANSPOSED (Cb[c*ldc+r]),
// 16 = qkv-split: col<512 -> Cb[r*512+c], col>=512 -> Cb2[(c-512)*NN + r] transposed
// 32 = concat-A: k0<128 from A=nfb (bf16, ld DIN); k0>=128 from gsrc (f32, ld DM), cvt on the fly
template <int FLAGS>
__global__ __launch_bounds__(256) void k_gemm_b(
    const ushort* __restrict__ A, int lda,
    const ushort* __restrict__ B, int ldb,
    float* __restrict__ Cf, ushort* __restrict__ Cb, ushort* __restrict__ Cb2, int ldc,
    int K, const float* __restrict__ bias, const float* __restrict__ gsrc) {
    __shared__ ushort As[128 * 64];
    __shared__ ushort Bs[128 * 64];
    const int tid = threadIdx.x;
    const int w = tid >> 6, l = tid & 63;
    const int l15 = l & 15, l4 = l >> 4;
    const int row0 = blockIdx.y * 128, col0 = blockIdx.x * 128;
    const int wm = (w >> 1) * 64, wn = (w & 1) * 64;
    f32x4 acc[4][4];
#pragma unroll
    for (int i = 0; i < 4; ++i)
#pragma unroll
        for (int j = 0; j < 4; ++j) acc[i][j] = (f32x4){0.f, 0.f, 0.f, 0.f};
    for (int k0 = 0; k0 < K; k0 += 64) {
#pragma unroll
        for (int i = 0; i < 4; ++i) {
            int ci = tid + 256 * i;
            int r = ci >> 3, s = ci & 7;
            if (FLAGS & 32) {
                if (k0 < 128) {
                    gl_lds16(A + (long)(row0 + r) * DIN + k0 + ((s ^ (r & 7)) * 8), &As[ci * 8]);
                } else {
                    const float* gp = gsrc + (long)(row0 + r) * DM + (k0 - 128) + s * 8;
                    float4 v0 = *(const float4*)(gp);
                    float4 v1 = *(const float4*)(gp + 4);
                    union { bf16x8 v; ushort u[8]; } pk;
                    pk.u[0] = f2b(v0.x); pk.u[1] = f2b(v0.y); pk.u[2] = f2b(v0.z); pk.u[3] = f2b(v0.w);
                    pk.u[4] = f2b(v1.x); pk.u[5] = f2b(v1.y); pk.u[6] = f2b(v1.z); pk.u[7] = f2b(v1.w);
                    *(bf16x8*)&As[r * 64 + ((s ^ (r & 7)) * 8)] = pk.v;
                }
            } else {
                gl_lds16(A + (long)(row0 + r) * lda + k0 + ((s ^ (r & 7)) * 8), &As[ci * 8]);
            }
            gl_lds16(B + (long)(col0 + r) * ldb + k0 + ((s ^ (r & 7)) * 8), &Bs[ci * 8]);
        }
        __syncthreads();
#pragma unroll
        for (int kk = 0; kk < 2; ++kk) {
            bf16x8 af[4], bfr[4];
#pragma unroll
            for (int i = 0; i < 4; ++i) {
                int ar = wm + i * 16 + l15;
                af[i] = *(const bf16x8*)&As[ar * 64 + (((kk * 4 + l4) ^ (ar & 7)) * 8)];
                int br = wn + i * 16 + l15;
                bfr[i] = *(const bf16x8*)&Bs[br * 64 + (((kk * 4 + l4) ^ (br & 7)) * 8)];
            }
#pragma unroll
            for (int i = 0; i < 4; ++i)
#pragma unroll
                for (int j = 0; j < 4; ++j)
                    acc[i][j] = __builtin_amdgcn_mfma_f32_16x16x32_bf16(af[i], bfr[j], acc[i][j], 0, 0, 0);
        }
        __syncthreads();
    }
#pragma unroll
    for (int i = 0; i < 4; ++i)
#pragma unroll
        for (int j = 0; j < 4; ++j) {
            int rb = row0 + wm + i * 16;
            int cb = col0 + wn + j * 16 + l15;
            float bv = bias ? bias[cb] : 0.f;
            if (FLAGS & 16) {
                if (cb < 512) {
#pragma unroll
                    for (int q = 0; q < 4; ++q)
                        Cb[(long)(rb + l4 * 4 + q) * 512 + cb] = f2b(acc[i][j][q] + bv);
                } else {
                    ushort4 o4;
                    o4.x = f2b(acc[i][j][0] + bv);
                    o4.y = f2b(acc[i][j][1] + bv);
                    o4.z = f2b(acc[i][j][2] + bv);
                    o4.w = f2b(acc[i][j][3] + bv);
                    *(ushort4*)(Cb2 + (long)(cb - 512) * NN + rb + l4 * 4) = o4;
                }
            } else if (FLAGS & 8) {
                ushort4 o4;
                o4.x = f2b(acc[i][j][0] + bv);
                o4.y = f2b(acc[i][j][1] + bv);
                o4.z = f2b(acc[i][j][2] + bv);
                o4.w = f2b(acc[i][j][3] + bv);
                *(ushort4*)(Cb + (long)cb * ldc + rb + l4 * 4) = o4;
            } else {
#pragma unroll
                for (int q = 0; q < 4; ++q) {
                    int r = rb + l4 * 4 + q;
                    float v = acc[i][j][q] + bv;
                    if (FLAGS & 4) v = fmaxf(v, 0.f);
                    if (FLAGS & 1) Cf[(long)r * ldc + cb] = v;
                    if (FLAGS & 2) Cb[(long)r * ldc + cb] = f2b(v);
                }
            }
        }
}

// ---------------- fused GEMM + residual + LayerNorm: x = LN(x + A@B^T + bias) ----------------
// COMB=1: A-tile is combined on the fly from NCH attention partials (opart, ml); each 64-col
// K-chunk is exactly one head. COMB=0: A staged via global_load_lds (pre-swizzled source).
template <int COMB>
__global__ __launch_bounds__(256) void k_gemm_ln(
    const ushort* __restrict__ A, int lda,
    const ushort* __restrict__ B, int ldb, int K,
    const float* __restrict__ bias,
    float* __restrict__ x, ushort* __restrict__ xb,
    const float* __restrict__ gam, const float* __restrict__ bet,
    const float* __restrict__ opart, const float2* __restrict__ ml) {
    __shared__ ushort As[16 * 64];    // 2 KB
    __shared__ ushort Bs[256 * 64];   // 32 KB
    __shared__ float red[4][16][2];
    const int tid = threadIdx.x;
    const int w = tid >> 6, l = tid & 63;
    const int l15 = l & 15, l4 = l >> 4;
    const int row0 = blockIdx.x * 16;
    f32x4 acc[4];
#pragma unroll
    for (int j = 0; j < 4; ++j) acc[j] = (f32x4){0.f, 0.f, 0.f, 0.f};
    for (int k0 = 0; k0 < K; k0 += 64) {
        if (tid < 128) {
            int r = tid >> 3, s = tid & 7;
            if (COMB) {
                // combine NCH chunk partials for head h = k0/64, cols d0..d0+7
                int row = row0 + r;
                int h = k0 >> 6;
                float2 m0 = ml[(0 * (long)NH + h) * NN + row];
                float2 m1 = ml[(1 * (long)NH + h) * NN + row];
                float2 m2 = ml[(2 * (long)NH + h) * NN + row];
                float2 m3 = ml[(3 * (long)NH + h) * NN + row];
                float M = fmaxf(fmaxf(m0.x, m1.x), fmaxf(m2.x, m3.x));
                float e0 = __expf(m0.x - M), e1 = __expf(m1.x - M);
                float e2 = __expf(m2.x - M), e3 = __expf(m3.x - M);
                float inv = 1.f / (m0.y * e0 + m1.y * e1 + m2.y * e2 + m3.y * e3);
                int d0 = s * 8;
                const float* p0 = opart + ((0 * (long)NH + h) * NN + row) * 64 + d0;
                const float* p1 = opart + ((1 * (long)NH + h) * NN + row) * 64 + d0;
                const float* p2 = opart + ((2 * (long)NH + h) * NN + row) * 64 + d0;
                const float* p3 = opart + ((3 * (long)NH + h) * NN + row) * 64 + d0;
                union { bf16x8 v; ushort u[8]; } pk;
#pragma unroll
                for (int j = 0; j < 8; ++j) {
                    float ov = e0 * p0[j] + e1 * p1[j] + e2 * p2[j] + e3 * p3[j];
                    pk.u[j] = f2b(ov * inv);
                }
                *(bf16x8*)&As[r * 64 + ((s ^ (r & 7)) * 8)] = pk.v;
            } else {
                gl_lds16(A + (long)(row0 + r) * lda + k0 + ((s ^ (r & 7)) * 8), &As[tid * 8]);
            }
        }
#pragma unroll
        for (int i = 0; i < 8; ++i) {
            int idx = i * 256 + tid;
            int r = idx >> 3, s = idx & 7;
            gl_lds16(B + (long)r * ldb + k0 + ((s ^ (r & 7)) * 8), &Bs[idx * 8]);
        }
        __syncthreads();
#pragma unroll
        for (int kk = 0; kk < 2; ++kk) {
            bf16x8 af = *(const bf16x8*)&As[l15 * 64 + (((kk * 4 + l4) ^ (l15 & 7)) * 8)];
#pragma unroll
            for (int j = 0; j < 4; ++j) {
                int br = w * 64 + j * 16 + l15;
                bf16x8 bfr = *(const bf16x8*)&Bs[br * 64 + (((kk * 4 + l4) ^ (br & 7)) * 8)];
                acc[j] = __builtin_amdgcn_mfma_f32_16x16x32_bf16(af, bfr, acc[j], 0, 0, 0);
            }
        }
        __syncthreads();
    }
    float val[4][4];
#pragma unroll
    for (int j = 0; j < 4; ++j) {
        int c = w * 64 + j * 16 + l15;
        float bv = bias[c];
#pragma unroll
        for (int q = 0; q < 4; ++q) {
            int r = row0 + l4 * 4 + q;
            val[j][q] = acc[j][q] + bv + x[(long)r * DM + c];
        }
    }
    float sum[4], sq[4];
#pragma unroll
    for (int q = 0; q < 4; ++q) {
        sum[q] = (val[0][q] + val[1][q]) + (val[2][q] + val[3][q]);
        sq[q] = (val[0][q] * val[0][q] + val[1][q] * val[1][q]) +
                (val[2][q] * val[2][q] + val[3][q] * val[3][q]);
    }
#pragma unroll
    for (int o = 1; o < 16; o <<= 1)
#pragma unroll
        for (int q = 0; q < 4; ++q) {
            sum[q] += __shfl_xor(sum[q], o);
            sq[q] += __shfl_xor(sq[q], o);
        }
    if (l15 == 0)
#pragma unroll
        for (int q = 0; q < 4; ++q) {
            red[w][l4 * 4 + q][0] = sum[q];
            red[w][l4 * 4 + q][1] = sq[q];
        }
    __syncthreads();
    float mean[4], rs[4];
#pragma unroll
    for (int q = 0; q < 4; ++q) {
        int rl = l4 * 4 + q;
        float ts = (red[0][rl][0] + red[1][rl][0]) + (red[2][rl][0] + red[3][rl][0]);
        float tq = (red[0][rl][1] + red[1][rl][1]) + (red[2][rl][1] + red[3][rl][1]);
        float m = ts * (1.f / 256.f);
        float var = tq * (1.f / 256.f) - m * m;
        mean[q] = m;
        rs[q] = rsqrtf(var + 1e-5f);
    }
#pragma unroll
    for (int j = 0; j < 4; ++j) {
        int c = w * 64 + j * 16 + l15;
        float gv = gam[c], bv = bet[c];
#pragma unroll
        for (int q = 0; q < 4; ++q) {
            int r = row0 + l4 * 4 + q;
            float ov = (val[j][q] - mean[q]) * rs[q] * gv + bv;
            x[(long)r * DM + c] = ov;
            xb[(long)r * DM + c] = f2b(ov);
        }
    }
}

// ---------------- GCN aggregation ----------------
template <int ACT, int B16>
__global__ void k_gcn_agg(const float* __restrict__ msg, const int* __restrict__ sc,
                          const int* __restrict__ csc_row, const float* __restrict__ dinv,
                          const float* __restrict__ bias,
                          float* __restrict__ outf, ushort* __restrict__ outb) {
    int j = blockIdx.x;
    int d = threadIdx.x;
    float acc = 0.f;
    int a = sc[j], b = sc[j + 1];
    for (int i = a; i < b; ++i) {
        int r = csc_row[i];
        acc += dinv[r] * msg[(long)r * DM + d];
    }
    float dj = dinv[j];
    float v = dj * acc + dj * dj * msg[(long)j * DM + d] + bias[d];
    if (ACT) v = fmaxf(v, 0.f);
    if (B16) outb[(long)j * DM + d] = f2b(v);
    else outf[(long)j * DM + d] = v;
}

// ---------------- flash attention: K+V staged in LDS (dbuf), counted vmcnt ----------------
__global__ __launch_bounds__(256, 4) void k_attn(
    const ushort* __restrict__ qkb, const ushort* __restrict__ vT,
    const int* __restrict__ bstart, const uint* __restrict__ entcomb,
    float* __restrict__ opart, float2* __restrict__ ml) {
    __shared__ ushort Klds[2][4096];  // [buf][r*64 + slot*8] linear, src pre-swizzled
    __shared__ ushort Vlds[2][4096];
    __shared__ ushort Pl[4096];       // per-wave 1024: P^T [16 q][64 kv] XOR-swizzled
    const int qb = blockIdx.x, h = blockIdx.y, cz = blockIdx.z;
    const int tid = threadIdx.x, w = tid >> 6, l = tid & 63;
    const int l15 = l & 15, l4 = l >> 4;
    bf16x8 qf[2];
    {
        const ushort* qp = qkb + (long)(qb * 64 + w * 16 + l15) * 512 + h * 64 + l4 * 8;
        qf[0] = *(const bf16x8*)(qp);
        qf[1] = *(const bf16x8*)(qp + 32);
    }
    const ushort* Kb = qkb + 256 + h * 64;          // row stride 512
    const ushort* Vb = vT + (long)(h * 64) * NN;    // row stride NN
    const uint* ec = entcomb + (long)h * NE;
    f32x4 o[4];
#pragma unroll
    for (int f = 0; f < 4; ++f) o[f] = (f32x4){0.f, 0.f, 0.f, 0.f};
    float m_run = -1e30f, l_run = 0.f;
    char* P = (char*)&Pl[w * 1024];
    const int bktW = (qb * 4 + w) * 64;
    const int t0 = cz * TPC;

    auto stage = [&](int b, int t) {
#pragma unroll
        for (int i = 0; i < 2; ++i) {
            int idx = i * 256 + tid;
            int r = idx >> 3, sl = idx & 7;
            gl_lds16(Kb + (long)(t * 64 + r) * 512 + ((sl ^ (r & 7)) * 8),
                     &Klds[b][idx * 8]);
            gl_lds16(Vb + (long)r * NN + t * 64 + ((sl ^ (r & 7)) * 8),
                     &Vlds[b][idx * 8]);
        }
    };

    int bs_c = bstart[bktW + t0], be_c = bstart[bktW + t0 + 1];
    stage(0, t0);
    int cur = 0;
    for (int tt = 0; tt < TPC; ++tt) {
        const int t = t0 + tt;
        asm volatile("s_waitcnt lgkmcnt(0)" ::: "memory");
        __builtin_amdgcn_s_barrier();
        int bs_n = 0, be_n = 0;
        if (tt + 1 < TPC) {
            stage(cur ^ 1, t + 1);
            bs_n = bstart[bktW + t + 1];
            be_n = bstart[bktW + t + 2];
            asm volatile("s_waitcnt vmcnt(4)" ::: "memory");  // my buf[cur] loads landed
        } else {
            asm volatile("s_waitcnt vmcnt(0)" ::: "memory");
        }
        __builtin_amdgcn_sched_barrier(0);
        __builtin_amdgcn_s_barrier();  // everyone's buf[cur] ready
        __builtin_amdgcn_sched_barrier(0);

        const ushort* Kl = Klds[cur];
        const ushort* Vl = Vlds[cur];
        // ---- S^T = K Q^T (Q pre-scaled) ----
        f32x4 s4[4];
#pragma unroll
        for (int f = 0; f < 4; ++f) {
            int kc = f * 16 + l15;
            bf16x8 k0 = *(const bf16x8*)&Kl[kc * 64 + ((l4 ^ (kc & 7)) * 8)];
            bf16x8 k1 = *(const bf16x8*)&Kl[kc * 64 + (((4 + l4) ^ (kc & 7)) * 8)];
            f32x4 a = (f32x4){0.f, 0.f, 0.f, 0.f};
            a = __builtin_amdgcn_mfma_f32_16x16x32_bf16(k0, qf[0], a, 0, 0, 0);
            a = __builtin_amdgcn_mfma_f32_16x16x32_bf16(k1, qf[1], a, 0, 0, 0);
            s4[f] = a;
        }
        // ---- sparse bias: precomputed sigmoid in high 16 bits (bf16) ----
        for (int i = bs_c; i < be_c; ++i) {
            uint e = ec[i];
            int r4 = (e >> 6) & 15, c6 = e & 63;
            if (l15 == r4 && ((c6 >> 2) & 3) == l4) {
                union { uint u; float f; } sv;
                sv.u = e & 0xFFFF0000u;
                float sig = sv.f;
                switch (((c6 >> 4) << 2) | (c6 & 3)) {
                    case 0:  s4[0][0] += sig; break; case 1:  s4[0][1] += sig; break;
                    case 2:  s4[0][2] += sig; break; case 3:  s4[0][3] += sig; break;
                    case 4:  s4[1][0] += sig; break; case 5:  s4[1][1] += sig; break;
                    case 6:  s4[1][2] += sig; break; case 7:  s4[1][3] += sig; break;
                    case 8:  s4[2][0] += sig; break; case 9:  s4[2][1] += sig; break;
                    case 10: s4[2][2] += sig; break; case 11: s4[2][3] += sig; break;
                    case 12: s4[3][0] += sig; break; case 13: s4[3][1] += sig; break;
                    case 14: s4[3][2] += sig; break; case 15: s4[3][3] += sig; break;
                }
            }
        }
        // ---- online softmax with defer-max (T13, THR=8) ----
        float ma = fmaxf(fmaxf(s4[0][0], s4[0][1]), fmaxf(s4[0][2], s4[0][3]));
        float mb = fmaxf(fmaxf(s4[1][0], s4[1][1]), fmaxf(s4[1][2], s4[1][3]));
        float mc = fmaxf(fmaxf(s4[2][0], s4[2][1]), fmaxf(s4[2][2], s4[2][3]));
        float md = fmaxf(fmaxf(s4[3][0], s4[3][1]), fmaxf(s4[3][2], s4[3][3]));
        float me = fmaxf(fmaxf(ma, mb), fmaxf(mc, md));
        me = fmaxf(me, __shfl_xor(me, 16));
        me = fmaxf(me, __shfl_xor(me, 32));
        if (!__all(me <= m_run + 8.f)) {
            float mn = fmaxf(m_run, me);
            float fac = __expf(m_run - mn);
            m_run = mn;
            l_run *= fac;
#pragma unroll
            for (int f = 0; f < 4; ++f)
#pragma unroll
                for (int r = 0; r < 4; ++r) o[f][r] *= fac;
        }
        float rp[4];
#pragma unroll
        for (int f = 0; f < 4; ++f) {
            float p0 = __expf(s4[f][0] - m_run);
            float p1 = __expf(s4[f][1] - m_run);
            float p2 = __expf(s4[f][2] - m_run);
            float p3 = __expf(s4[f][3] - m_run);
            s4[f][0] = p0; s4[f][1] = p1; s4[f][2] = p2; s4[f][3] = p3;
            rp[f] = (p0 + p1) + (p2 + p3);
        }
        float rsum = (rp[0] + rp[1]) + (rp[2] + rp[3]);
        rsum += __shfl_xor(rsum, 16);
        rsum += __shfl_xor(rsum, 32);
        l_run += rsum;
        // ---- P^T -> per-wave LDS (bf16 pairs, slot-XOR swizzled) ----
#pragma unroll
        for (int f = 0; f < 4; ++f)
#pragma unroll
            for (int p = 0; p < 2; ++p) {
                uint u = cvt_pk_bf16(s4[f][2 * p], s4[f][2 * p + 1]);
                int slot = f * 2 + (l4 >> 1);
                int byte = l15 * 128 + ((slot ^ (l15 & 7)) << 4) + (l4 & 1) * 8 + p * 4;
                *(uint*)(P + byte) = u;
            }
        asm volatile("s_waitcnt lgkmcnt(0)" ::: "memory");
        __builtin_amdgcn_sched_barrier(0);
        // ---- O^T += V^T P^T ----
#pragma unroll
        for (int ks = 0; ks < 2; ++ks) {
            bf16x8 pb = *(const bf16x8*)(P + l15 * 128 + (((ks * 4 + l4) ^ (l15 & 7)) << 4));
#pragma unroll
            for (int fd = 0; fd < 4; ++fd) {
                int d = fd * 16 + l15;
                bf16x8 vfr = *(const bf16x8*)&Vl[d * 64 + (((ks * 4 + l4) ^ (d & 7)) * 8)];
                o[fd] = __builtin_amdgcn_mfma_f32_16x16x32_bf16(vfr, pb, o[fd], 0, 0, 0);
            }
        }
        bs_c = bs_n; be_c = be_n;
        cur ^= 1;
    }
    // ---- write partials: O^T lane q = l15, d = fd*16 + l4*4 + r ----
    long base = (((long)cz * NH + h) * NN + qb * 64 + w * 16 + l15) * 64;
#pragma unroll
    for (int fd = 0; fd < 4; ++fd)
#pragma unroll
        for (int r = 0; r < 4; ++r)
            opart[base + fd * 16 + l4 * 4 + r] = o[fd][r];
    if (l4 == 0)
        ml[((long)cz * NH + h) * NN + qb * 64 + w * 16 + l15] = make_float2(m_run, l_run);
}

// ---------------- output ----------------

__global__ void k_out(const float* __restrict__ x, const float* __restrict__ w,
                      const float* __restrict__ b, float* __restrict__ out) {
    int row = blockIdx.x;
    int lane = threadIdx.x;
    float s = 0.f;
#pragma unroll
    for (int i = 0; i < 4; ++i) s += x[(long)row * DM + lane + 64 * i] * w[lane + 64 * i];
#pragma unroll
    for (int o = 1; o < 64; o <<= 1) s += __shfl_xor(s, o);
    if (lane == 0) out[row] = 1.f / (1.f + expf(-(s + b[0])));
}

__global__ void k_sentinel(float* out, int n) {
    int i = blockIdx.x * 256 + threadIdx.x;
    if (i < n) out[i] = 1.0e9f;
}

// ---------------- host ----------------

extern "C" void kernel_launch(void* const* d_in, const int* in_sizes, int n_in,
                              void* d_out, int out_size, void* d_ws, size_t ws_size,
                              hipStream_t stream) {
    const float* nf = (const float*)d_in[0];
    const int* ei = (const int*)d_in[1];
    const int* erow = ei;
    const int* ecol = ei + NE;
    const float* gcn1_w = (const float*)d_in[2];
    const float* gcn1_b = (const float*)d_in[3];
    const float* gcn2_w = (const float*)d_in[4];
    const float* gcn2_b = (const float*)d_in[5];
    const float* edge_w = (const float*)d_in[6];
    const float* edge_b = (const float*)d_in[7];
    const float* proj_w = (const float*)d_in[8];
    const float* proj_b = (const float*)d_in[9];
    const float* wqkv = (const float*)d_in[10];
    const float* bqkv = (const float*)d_in[11];
    const float* wo = (const float*)d_in[12];
    const float* bo = (const float*)d_in[13];
    const float* ffn_w1 = (const float*)d_in[14];
    const float* ffn_b1 = (const float*)d_in[15];
    const float* ffn_w2 = (const float*)d_in[16];
    const float* ffn_b2 = (const float*)d_in[17];
    const float* ln1_g = (const float*)d_in[18];
    const float* ln1_b = (const float*)d_in[19];
    const float* ln2_g = (const float*)d_in[20];
    const float* ln2_b = (const float*)d_in[21];
    const float* out_w = (const float*)d_in[22];
    const float* out_b = (const float*)d_in[23];
    float* out = (float*)d_out;

    char* wp = (char*)d_ws;
    size_t off = 0;
    auto alloc = [&](size_t bytes) -> void* {
        void* p = wp + off;
        off = (off + bytes + 255) & ~(size_t)255;
        return p;
    };
    // big union block (16 MB): msg (GCN) / opart (attn) / ffnHb (ffn)
    char* big = (char*)alloc((size_t)NCH * NH * NN * 64 * 4);
    float* msg = (float*)big;
    float* opart = (float*)big;
    ushort* ffnHb = (ushort*)big;  // 8 MB
    float* x = (float*)alloc((size_t)NN * DM * 4);
    ushort* xb = (ushort*)alloc((size_t)NN * DM * 2);
    ushort* hb = (ushort*)alloc((size_t)NN * DM * 2);
    float* g = (float*)alloc((size_t)NN * DM * 4);
    ushort* qkb = (ushort*)alloc((size_t)NN * 512 * 2);
    ushort* vT = (ushort*)alloc((size_t)DM * NN * 2);
    float2* ml = (float2*)alloc((size_t)NCH * NH * NN * 8);
    ushort* nfb = (ushort*)alloc((size_t)NN * DIN * 2);
    ushort* wqkvb = (ushort*)alloc((size_t)NL * 768 * DM * 2);
    ushort* wob = (ushort*)alloc((size_t)NL * DM * DM * 2);
    ushort* f1b = (ushort*)alloc((size_t)NL * 1024 * DM * 2);
    ushort* f2bw = (ushort*)alloc((size_t)NL * DM * 1024 * 2);
    ushort* g1b = (ushort*)alloc((size_t)DM * DIN * 2);
    ushort* g2b = (ushort*)alloc((size_t)DM * DM * 2);
    ushort* pjb = (ushort*)alloc((size_t)DM * 384 * 2);
    float* bq2 = (float*)alloc((size_t)NL * 768 * 4);
    uint* bitmap = (uint*)alloc((size_t)NN * NN / 8);
    unsigned char* flag = (unsigned char*)alloc(NE);
    int* cnt_c = (int*)alloc((size_t)NN * 4);
    int* bcnt = (int*)alloc((size_t)NBKT * 4);
    int* sc = (int*)alloc((size_t)(NN + 1) * 4);
    int* bstart = (int*)alloc((size_t)(NBKT + 1) * 4);
    int* fc = (int*)alloc((size_t)NN * 4);
    int* bfill = (int*)alloc((size_t)NBKT * 4);
    int* csc_row = (int*)alloc((size_t)NE * 4);
    uint* entcomb = (uint*)alloc((size_t)NH * NE * 4);
    float* dinv = (float*)alloc((size_t)NN * 4);

    if (off > ws_size) {
        k_sentinel<<<(out_size + 255) / 256, 256, 0, stream>>>(out, out_size);
        return;
    }

    // ---- preprocessing ----
    hipMemsetAsync(bitmap, 0, (size_t)NN * NN / 8, stream);
    hipMemsetAsync(cnt_c, 0, NN * 4, stream);
    hipMemsetAsync(bcnt, 0, NBKT * 4, stream);
    hipMemsetAsync(fc, 0, NN * 4, stream);
    hipMemsetAsync(bfill, 0, NBKT * 4, stream);
    k_edge1<<<NE / 256, 256, 0, stream>>>(erow, ecol, bitmap, cnt_c, bcnt, flag);
    k_scan<NN><<<1, 256, 0, stream>>>(cnt_c, sc);
    k_scan<NBKT><<<1, 256, 0, stream>>>(bcnt, bstart);
    k_edge2<<<NE / 256, 256, 0, stream>>>(erow, ecol, flag, sc, fc, csc_row, bstart, bfill,
                                          entcomb, edge_w, edge_b);
    k_dinv<<<NN / 256, 256, 0, stream>>>(cnt_c, dinv);

    // ---- weight/input conversion ----
    CvtP cp;
    cp.s[0] = nf;      cp.d[0] = nfb;   cp.n[0] = NN * DIN;
    cp.s[1] = wqkv;    cp.d[1] = wqkvb; cp.n[1] = NL * 768 * DM;
    cp.s[2] = wo;      cp.d[2] = wob;   cp.n[2] = NL * DM * DM;
    cp.s[3] = ffn_w1;  cp.d[3] = f1b;   cp.n[3] = NL * 1024 * DM;
    cp.s[4] = ffn_w2;  cp.d[4] = f2bw;  cp.n[4] = NL * DM * 1024;
    cp.s[5] = gcn1_w;  cp.d[5] = g1b;   cp.n[5] = DM * DIN;
    cp.s[6] = gcn2_w;  cp.d[6] = g2b;   cp.n[6] = DM * DM;
    cp.s[7] = proj_w;  cp.d[7] = pjb;   cp.n[7] = DM * 384;
    k_cvt<<<dim3(768, 8), 256, 0, stream>>>(cp);
    k_scaleb<<<(NL * 768 + 255) / 256, 256, 0, stream>>>(bqkv, bq2);

    // ---- GCN ----
    k_gemm_b<1><<<dim3(DM / 128, NN / 128), 256, 0, stream>>>(
        nfb, DIN, g1b, DIN, msg, nullptr, nullptr, DM, DIN, nullptr, nullptr);
    k_gcn_agg<1, 1><<<NN, DM, 0, stream>>>(msg, sc, csc_row, dinv, gcn1_b, nullptr, hb);
    k_gemm_b<1><<<dim3(DM / 128, NN / 128), 256, 0, stream>>>(
        hb, DM, g2b, DM, msg, nullptr, nullptr, DM, DM, nullptr, nullptr);
    k_gcn_agg<0, 0><<<NN, DM, 0, stream>>>(msg, sc, csc_row, dinv, gcn2_b, g, nullptr);
    // ---- proj with fused concat: A = [nfb | bf16(g)] ----
    k_gemm_b<35><<<dim3(DM / 128, NN / 128), 256, 0, stream>>>(
        nfb, DIN, pjb, 384, x, xb, nullptr, DM, 384, proj_b, g);

    for (int l = 0; l < NL; ++l) {
        // merged qkv: q,k -> qkb [n][512] (q pre-scaled); v -> vT [256][NN] transposed
        k_gemm_b<18><<<dim3(768 / 128, NN / 128), 256, 0, stream>>>(
            xb, DM, wqkvb + (long)l * 768 * DM, DM, nullptr, qkb, vT, 512, DM,
            bq2 + (long)l * 768, nullptr);
        k_attn<<<dim3(NN / 64, NH, NCH), 256, 0, stream>>>(
            qkb, vT, bstart, entcomb, opart, ml);
        // fused: x = LN1(x + comb(opart,ml) @ wo^T + bo)
        k_gemm_ln<1><<<NN / 16, 256, 0, stream>>>(
            nullptr, DM, wob + (long)l * DM * DM, DM, DM, bo + (long)l * DM,
            x, xb, ln1_g + (long)l * DM, ln1_b + (long)l * DM, opart, ml);
        k_gemm_b<6><<<dim3(1024 / 128, NN / 128), 256, 0, stream>>>(
            xb, DM, f1b + (long)l * 1024 * DM, DM, nullptr, ffnHb, nullptr, 1024, DM,
            ffn_b1 + (long)l * 1024, nullptr);
        // fused: x = LN2(x + ffnH @ w2^T + b2)
        k_gemm_ln<0><<<NN / 16, 256, 0, stream>>>(
            ffnHb, 1024, f2bw + (long)l * DM * 1024, 1024, 1024, ffn_b2 + (long)l * DM,
            x, xb, ln2_g + (long)l * DM, ln2_b + (long)l * DM, nullptr, nullptr);
    }
    k_out<<<NN, 64, 0, stream>>>(x, out_w, out_b, out);
}